// Round 1
// baseline (864.106 us; speedup 1.0000x reference)
//
#include <hip/hip_runtime.h>
#include <hip/hip_bf16.h>
#include <hip/hip_fp16.h>
#include <hip/hip_cooperative_groups.h>

namespace cg = cooperative_groups;

// ---------------------------------------------------------------------------
// GCN link prediction. Round 15: the round-14 pipeline (verified) fused into
// ONE cooperative kernel with 8 grid.sync()s. Theory: 10 serialized dispatches
// cost ~15-20us each in boundary overhead (sum-of-rooflines ~70us vs 259us
// measured; rocprof top-5 shows no pipeline kernel above 42us). gemm1 is
// overlapped with the CSR bucket-prefix phase on disjoint blocks.
// Fallback: if cooperative launch fails cleanly, run the old 10-kernel path.
// ---------------------------------------------------------------------------

typedef _Float16 half8 __attribute__((ext_vector_type(8)));
typedef _Float16 half4v __attribute__((ext_vector_type(4)));
typedef float   floatx4 __attribute__((ext_vector_type(4)));

#define NBLK 256   // fallback path: blocks for edge-chunk passes
#define GMAX 1024  // max cooperative grid (4 blocks/CU x 256 CUs)

// ---------------------------------------------------------------------------
// Shared device bodies (verbatim round-14 logic, parameterized)
// ---------------------------------------------------------------------------

template<int M>
__device__ __forceinline__ void gemm_tile(const _Float16* __restrict__ Xh,
                                          const _Float16* __restrict__ Wt,
                                          _Float16* __restrict__ Y,
                                          int N, int tile, int t) {
  constexpr int K = 128;
  constexpr int CT = M / 16;
  const int lane = t & 63;
  const int i16 = lane & 15;
  const int quad = lane >> 4;
  const int row0 = tile * 64 + (t >> 6) * 16;
  int arow = row0 + i16;
  if (arow >= N) arow = N - 1;
  const _Float16* aptr = Xh + (size_t)arow * K + quad * 8;
  floatx4 acc[CT];
#pragma unroll
  for (int c = 0; c < CT; ++c) acc[c] = (floatx4){0.f, 0.f, 0.f, 0.f};
#pragma unroll
  for (int k0 = 0; k0 < K; k0 += 32) {
    half8 a = *(const half8*)(aptr + k0);
#pragma unroll
    for (int c = 0; c < CT; ++c) {
      half8 b = *(const half8*)(Wt + (size_t)(c * 16 + i16) * K + quad * 8 + k0);
      acc[c] = __builtin_amdgcn_mfma_f32_16x16x32_f16(a, b, acc[c], 0, 0, 0);
    }
  }
#pragma unroll
  for (int c = 0; c < CT; ++c) {
#pragma unroll
    for (int r = 0; r < 4; ++r) {
      int gr = row0 + quad * 4 + r;
      if (gr < N) Y[(size_t)gr * M + c * 16 + i16] = (_Float16)acc[c][r];
    }
  }
}

// Broadcast edge j's (src, dis) with UNIFORM shfl indices; zero weight if
// j >= m (src clamped to edge k's — always valid).
#define BCAST(j, svar, dvar)                          \
  {                                                   \
    int jj = (j) < m ? (j) : k;                       \
    svar = __shfl(er, jj, 64);                        \
    dvar = ((j) < m) ? __shfl(dr, jj, 64) : 0.f;      \
  }

template<bool RELU>
__device__ __forceinline__ void agg128_body(
    const __half* __restrict__ xw, const int* __restrict__ row_ptr,
    const int* __restrict__ ep, const float* __restrict__ dis,
    const float* __restrict__ deg_inv, const float* __restrict__ bias,
    __half* __restrict__ out, int node, int lane) {
  const int s0 = row_ptr[node], s1 = row_ptr[node + 1];
  const int sub = lane & 15;
  const int quarter = lane >> 4;
  const float disc = dis[node];
  float a0[8], a1[8];
#pragma unroll
  for (int j = 0; j < 8; ++j) { a0[j] = 0.f; a1[j] = 0.f; }
  for (int base = s0; base < s1; base += 64) {
    int m = s1 - base; if (m > 64) m = 64;   // wave-uniform
    int er = 0; float dr = 0.f;
    if (lane < m) { er = ep[base + lane]; dr = dis[er]; }
    for (int k = 0; k < m; k += 8) {
      {
        int sA, sB, sC, sD; float dA, dB, dC, dD;
        BCAST(k,     sA, dA); BCAST(k + 1, sB, dB);
        BCAST(k + 2, sC, dC); BCAST(k + 3, sD, dD);
        int   s = (quarter == 0) ? sA : (quarter == 1) ? sB : (quarter == 2) ? sC : sD;
        float w = ((quarter == 0) ? dA : (quarter == 1) ? dB : (quarter == 2) ? dC : dD) * disc;
        float4 raw = ((const float4*)(xw + (size_t)s * 128))[sub];
        const __half2* hp = (const __half2*)&raw;
#pragma unroll
        for (int j = 0; j < 4; ++j) {
          float2 v = __half22float2(hp[j]);
          a0[2 * j]     = fmaf(w, v.x, a0[2 * j]);
          a0[2 * j + 1] = fmaf(w, v.y, a0[2 * j + 1]);
        }
      }
      if (k + 4 < m) {
        int sA, sB, sC, sD; float dA, dB, dC, dD;
        BCAST(k + 4, sA, dA); BCAST(k + 5, sB, dB);
        BCAST(k + 6, sC, dC); BCAST(k + 7, sD, dD);
        int   s = (quarter == 0) ? sA : (quarter == 1) ? sB : (quarter == 2) ? sC : sD;
        float w = ((quarter == 0) ? dA : (quarter == 1) ? dB : (quarter == 2) ? dC : dD) * disc;
        float4 raw = ((const float4*)(xw + (size_t)s * 128))[sub];
        const __half2* hp = (const __half2*)&raw;
#pragma unroll
        for (int j = 0; j < 4; ++j) {
          float2 v = __half22float2(hp[j]);
          a1[2 * j]     = fmaf(w, v.x, a1[2 * j]);
          a1[2 * j + 1] = fmaf(w, v.y, a1[2 * j + 1]);
        }
      }
    }
  }
#pragma unroll
  for (int j = 0; j < 8; ++j) {
    a0[j] += a1[j];
    a0[j] += __shfl_xor(a0[j], 16, 64);
    a0[j] += __shfl_xor(a0[j], 32, 64);
  }
  if (quarter == 0) {
    float di = deg_inv[node];
    float4 sraw = ((const float4*)(xw + (size_t)node * 128))[sub];
    const __half2* sp = (const __half2*)&sraw;
    const float4* bp = (const float4*)(bias + 8 * sub);
    float o[8];
#pragma unroll
    for (int j = 0; j < 4; ++j) {
      float2 sv = __half22float2(sp[j]);
      o[2 * j]     = a0[2 * j]     + sv.x * di;
      o[2 * j + 1] = a0[2 * j + 1] + sv.y * di;
    }
    float4 b0 = bp[0], b1v = bp[1];
    o[0] += b0.x; o[1] += b0.y; o[2] += b0.z; o[3] += b0.w;
    o[4] += b1v.x; o[5] += b1v.y; o[6] += b1v.z; o[7] += b1v.w;
    if (RELU) {
#pragma unroll
      for (int j = 0; j < 8; ++j) o[j] = fmaxf(o[j], 0.f);
    }
    __half2 h2[4];
#pragma unroll
    for (int j = 0; j < 4; ++j)
      h2[j] = __float22half2_rn(make_float2(o[2 * j], o[2 * j + 1]));
    *(float4*)(out + (size_t)node * 128 + 8 * sub) = *(const float4*)h2;
  }
}

template<bool RELU>
__device__ __forceinline__ void agg64_body(
    const __half* __restrict__ xw, const int* __restrict__ row_ptr,
    const int* __restrict__ ep, const float* __restrict__ dis,
    const float* __restrict__ deg_inv, const float* __restrict__ bias,
    __half* __restrict__ out, int node, int lane) {
  const int s0 = row_ptr[node], s1 = row_ptr[node + 1];
  const int sub = lane & 15;
  const int quarter = lane >> 4;
  const float disc = dis[node];
  float a0[4], a1[4];
#pragma unroll
  for (int j = 0; j < 4; ++j) { a0[j] = 0.f; a1[j] = 0.f; }
  for (int base = s0; base < s1; base += 64) {
    int m = s1 - base; if (m > 64) m = 64;
    int er = 0; float dr = 0.f;
    if (lane < m) { er = ep[base + lane]; dr = dis[er]; }
    for (int k = 0; k < m; k += 8) {
      {
        int sA, sB, sC, sD; float dA, dB, dC, dD;
        BCAST(k,     sA, dA); BCAST(k + 1, sB, dB);
        BCAST(k + 2, sC, dC); BCAST(k + 3, sD, dD);
        int   s = (quarter == 0) ? sA : (quarter == 1) ? sB : (quarter == 2) ? sC : sD;
        float w = ((quarter == 0) ? dA : (quarter == 1) ? dB : (quarter == 2) ? dC : dD) * disc;
        float2 raw = ((const float2*)(xw + (size_t)s * 64))[sub];
        const __half2* hp = (const __half2*)&raw;
#pragma unroll
        for (int j = 0; j < 2; ++j) {
          float2 v = __half22float2(hp[j]);
          a0[2 * j]     = fmaf(w, v.x, a0[2 * j]);
          a0[2 * j + 1] = fmaf(w, v.y, a0[2 * j + 1]);
        }
      }
      if (k + 4 < m) {
        int sA, sB, sC, sD; float dA, dB, dC, dD;
        BCAST(k + 4, sA, dA); BCAST(k + 5, sB, dB);
        BCAST(k + 6, sC, dC); BCAST(k + 7, sD, dD);
        int   s = (quarter == 0) ? sA : (quarter == 1) ? sB : (quarter == 2) ? sC : sD;
        float w = ((quarter == 0) ? dA : (quarter == 1) ? dB : (quarter == 2) ? dC : dD) * disc;
        float2 raw = ((const float2*)(xw + (size_t)s * 64))[sub];
        const __half2* hp = (const __half2*)&raw;
#pragma unroll
        for (int j = 0; j < 2; ++j) {
          float2 v = __half22float2(hp[j]);
          a1[2 * j]     = fmaf(w, v.x, a1[2 * j]);
          a1[2 * j + 1] = fmaf(w, v.y, a1[2 * j + 1]);
        }
      }
    }
  }
#pragma unroll
  for (int j = 0; j < 4; ++j) {
    a0[j] += a1[j];
    a0[j] += __shfl_xor(a0[j], 16, 64);
    a0[j] += __shfl_xor(a0[j], 32, 64);
  }
  if (quarter == 0) {
    float di = deg_inv[node];
    float2 sraw = ((const float2*)(xw + (size_t)node * 64))[sub];
    const __half2* sp = (const __half2*)&sraw;
    float4 bv = ((const float4*)(bias))[sub];
    float2 s0v = __half22float2(sp[0]);
    float2 s1v = __half22float2(sp[1]);
    float o0 = a0[0] + s0v.x * di + bv.x;
    float o1 = a0[1] + s0v.y * di + bv.y;
    float o2 = a0[2] + s1v.x * di + bv.z;
    float o3 = a0[3] + s1v.y * di + bv.w;
    if (RELU) {
      o0 = fmaxf(o0, 0.f); o1 = fmaxf(o1, 0.f);
      o2 = fmaxf(o2, 0.f); o3 = fmaxf(o3, 0.f);
    }
    __half2 h2[2];
    h2[0] = __float22half2_rn(make_float2(o0, o1));
    h2[1] = __float22half2_rn(make_float2(o2, o3));
    *(float2*)(out + (size_t)node * 64 + 4 * sub) = *(const float2*)h2;
  }
}

// ---------------------------------------------------------------------------
// The fused cooperative kernel
// ---------------------------------------------------------------------------

struct MegaArgs {
  const float* x; const float* W1; const float* b1; const float* W2; const float* b2;
  const int* row; const int* col; const int* eli;
  float* out;
  float* dis; float* dinv; int* rowp;
  int* bhist; int* base; int* bs; int* tot;
  int2* tmp; int* ep;
  _Float16* Xh; _Float16* W1t; _Float16* W2t;
  __half* bufA; __half* bufB; __half* bufC; __half* z;
  int N, E, NL, B, n4, cs;
};

__global__ __launch_bounds__(256, 4)
void mega_kernel(MegaArgs A) {
  cg::grid_group grid = cg::this_grid();
  const int t = threadIdx.x;
  const int bid = blockIdx.x;
  const int G = gridDim.x;
  __shared__ int sm[3 * 256];

  // ---- Phase A: prep (x->fp16, W transposes) + per-chunk bucket histogram --
  {
    const int gs = G * 256;
    for (int i = bid * 256 + t; i < A.n4; i += gs) {
      float4 v = ((const float4*)A.x)[i];
      half4v h; h[0] = (_Float16)v.x; h[1] = (_Float16)v.y;
      h[2] = (_Float16)v.z; h[3] = (_Float16)v.w;
      ((half4v*)A.Xh)[i] = h;
      if (i < 128 * 128) { int k = i >> 7, n = i & 127; A.W1t[(size_t)n * 128 + k] = (_Float16)A.W1[i]; }
      if (i < 128 * 64)  { int k = i >> 6, n = i & 63;  A.W2t[(size_t)n * 128 + k] = (_Float16)A.W2[i]; }
    }
    // histogram of bucket = col>>8 for this block's chunk (chunk == bid)
    for (int b = t; b < A.B; b += 256) sm[b] = 0;
    __syncthreads();
    int e0 = bid * A.cs, e1 = min(A.E, e0 + A.cs);
    for (int i = e0 + t; i < e1; i += 256)
      atomicAdd(&sm[A.col[i] >> 8], 1);
    __syncthreads();
    for (int b = t; b < A.B; b += 256) A.bhist[(size_t)bid * A.B + b] = sm[b];
  }
  grid.sync();

  // ---- Phase B: per-bucket chunk-prefix (blocks 0..BK-1, wave per bucket)
  //      OVERLAPPED with gemm1 on the remaining blocks -----------------------
  {
    const int BK = (A.B + 3) >> 2;
    if (bid < BK) {
      int k = (bid << 2) + (t >> 6);
      int lane = t & 63;
      if (k < A.B) {
        int run = 0;
        for (int c0 = 0; c0 < G; c0 += 64) {
          int c = c0 + lane;
          int v = (c < G) ? A.bhist[(size_t)c * A.B + k] : 0;
          int p = v;
#pragma unroll
          for (int d = 1; d < 64; d <<= 1) {
            int o = __shfl_up(p, d, 64);
            if (lane >= d) p += o;
          }
          if (c < G) A.base[(size_t)c * A.B + k] = run + (p - v);
          run += __shfl(p, 63, 64);
        }
        if (lane == 0) A.tot[k] = run;
      }
    } else {
      const int TG = (A.N + 63) >> 6;
      for (int tile = bid - BK; tile < TG; tile += G - BK)
        gemm_tile<128>(A.Xh, A.W1t, (_Float16*)A.bufA, A.N, tile, t);
    }
  }
  grid.sync();

  // ---- Phase C: bucket-start scan (block 0 only; tiny) ---------------------
  if (bid == 0) {
    for (int b = t; b < A.B; b += 256) sm[b] = A.tot[b];
    __syncthreads();
    if (t == 0) {
      int run = 0;
      for (int b = 0; b < A.B; ++b) { int v = sm[b]; sm[b] = run; run += v; }
      sm[A.B] = run;
    }
    __syncthreads();
    for (int b = t; b <= A.B; b += 256) A.bs[b] = sm[b];
  }
  grid.sync();

  // ---- Phase D: scatter edges into bucket-grouped tmp ----------------------
  {
    for (int b = t; b < A.B; b += 256)
      sm[b] = A.bs[b] + A.base[(size_t)bid * A.B + b];
    __syncthreads();
    int e0 = bid * A.cs, e1 = min(A.E, e0 + A.cs);
    for (int i = e0 + t; i < e1; i += 256) {
      int cc = A.col[i];
      int pos = atomicAdd(&sm[cc >> 8], 1);
      A.tmp[pos] = make_int2(A.row[i], cc);
    }
  }
  grid.sync();

  // ---- Phase E: per-bucket CSR finalize (rowp, dis, dinv, ep) --------------
  for (int b = bid; b < A.B; b += G) {
    int* h  = sm;
    int* lo = sm + 256;
    int* cur = sm + 512;
    h[t] = 0;
    __syncthreads();
    int s0 = A.bs[b], s1 = A.bs[b + 1];
    for (int i = s0 + t; i < s1; i += 256)
      atomicAdd(&h[A.tmp[i].y & 255], 1);
    __syncthreads();
    if (t == 0) {
      int run = 0;
      for (int cb = 0; cb < 256; ++cb) { lo[cb] = run; run += h[cb]; }
    }
    __syncthreads();
    cur[t] = lo[t];
    int node = (b << 8) + t;
    if (node < A.N) {
      int c = h[t];
      A.rowp[node] = s0 + lo[t];
      float d = (float)(c + 1);   // +1 self loop
      A.dinv[node] = 1.0f / d;
      A.dis[node]  = rsqrtf(d);
      if (node == A.N - 1) A.rowp[A.N] = s1;
    }
    __syncthreads();
    for (int i = s0 + t; i < s1; i += 256) {
      int2 rc = A.tmp[i];
      int r = atomicAdd(&cur[rc.y & 255], 1);
      A.ep[s0 + r] = rc.x;
    }
    __syncthreads();
  }
  grid.sync();

  // ---- Phase F: agg128 + relu (conv1 finish) -------------------------------
  {
    const int gw = (bid << 2) + (t >> 6);
    const int nw = G << 2;
    const int lane = t & 63;
    for (int node = gw; node < A.N; node += nw)
      agg128_body<true>(A.bufA, A.rowp, A.ep, A.dis, A.dinv, A.b1, A.bufB, node, lane);
  }
  grid.sync();

  // ---- Phase G: gemm2 ------------------------------------------------------
  {
    const int TG = (A.N + 63) >> 6;
    for (int tile = bid; tile < TG; tile += G)
      gemm_tile<64>((const _Float16*)A.bufB, A.W2t, (_Float16*)A.bufC, A.N, tile, t);
  }
  grid.sync();

  // ---- Phase H: agg64 (conv2 finish) ---------------------------------------
  {
    const int gw = (bid << 2) + (t >> 6);
    const int nw = G << 2;
    const int lane = t & 63;
    for (int node = gw; node < A.N; node += nw)
      agg64_body<false>(A.bufC, A.rowp, A.ep, A.dis, A.dinv, A.b2, A.z, node, lane);
  }
  grid.sync();

  // ---- Phase I: decode -----------------------------------------------------
  {
    const int gw = (bid << 2) + (t >> 6);
    const int nw = G << 2;
    const int lane = t & 63;
    for (int w = gw; w < A.NL; w += nw) {
      int src = A.eli[w];
      int dst = A.eli[A.NL + w];
      int node = (lane < 32) ? src : dst;
      int sub = lane & 31;
      float2 v = __half22float2(((const __half2*)(A.z + (size_t)node * 64))[sub]);
      float ox = __shfl_xor(v.x, 32, 64);
      float oy = __shfl_xor(v.y, 32, 64);
      float p = v.x * ox + v.y * oy;
#pragma unroll
      for (int mm = 16; mm >= 1; mm >>= 1) p += __shfl_xor(p, mm, 64);
      if (lane == 0) A.out[w] = p;
    }
  }
}

// ---------------------------------------------------------------------------
// Fallback path: round-14 kernels, unchanged (used only if cooperative launch
// is rejected by the runtime/capture).
// ---------------------------------------------------------------------------

__global__ __launch_bounds__(256)
void prep_kernel(const float* __restrict__ x, const float* __restrict__ W1,
                 const float* __restrict__ W2, _Float16* __restrict__ Xh,
                 _Float16* __restrict__ W1t, _Float16* __restrict__ W2t, int n4) {
  int i = blockIdx.x * 256 + threadIdx.x;
  if (i < n4) {
    float4 v = ((const float4*)x)[i];
    half4v h; h[0] = (_Float16)v.x; h[1] = (_Float16)v.y;
    h[2] = (_Float16)v.z; h[3] = (_Float16)v.w;
    ((half4v*)Xh)[i] = h;
  }
  if (i < 128 * 128) { int k = i >> 7, n = i & 127; W1t[(size_t)n * 128 + k] = (_Float16)W1[i]; }
  if (i < 128 * 64)  { int k = i >> 6, n = i & 63;  W2t[(size_t)n * 128 + k] = (_Float16)W2[i]; }
}

__global__ __launch_bounds__(256)
void hist_kernel(const int* __restrict__ col, int* __restrict__ bhist,
                 int ne, int chunk, int B) {
  __shared__ int h[256];
  int t = threadIdx.x, blk = blockIdx.x;
  for (int b = t; b < B; b += 256) h[b] = 0;
  __syncthreads();
  int e0 = blk * chunk, e1 = min(ne, e0 + chunk);
  for (int i = e0 + t; i < e1; i += 256)
    atomicAdd(&h[col[i] >> 8], 1);
  __syncthreads();
  for (int b = t; b < B; b += 256) bhist[blk * B + b] = h[b];
}

__global__ __launch_bounds__(256)
void base_kernel(const int* __restrict__ bhist, int* __restrict__ base,
                 int* __restrict__ bs, int B) {
  __shared__ int tot[256];
  __shared__ int start[257];
  int t = threadIdx.x;
  if (t < B) {
    int s = 0;
    for (int blk = 0; blk < NBLK; ++blk) s += bhist[blk * B + t];
    tot[t] = s;
  }
  __syncthreads();
  if (t == 0) {
    int run = 0;
    for (int b = 0; b < B; ++b) { start[b] = run; run += tot[b]; }
    start[B] = run;
  }
  __syncthreads();
  if (t <= B) bs[t] = start[t];
  if (t < B) {
    int run = start[t];
    for (int blk = 0; blk < NBLK; ++blk) {
      base[blk * B + t] = run;
      run += bhist[blk * B + t];
    }
  }
}

__global__ __launch_bounds__(256)
void bucket_scatter_kernel(const int* __restrict__ row, const int* __restrict__ col,
                           const int* __restrict__ base, int2* __restrict__ tmp,
                           int ne, int chunk, int B) {
  __shared__ int cur[256];
  int t = threadIdx.x, blk = blockIdx.x;
  for (int b = t; b < B; b += 256) cur[b] = base[blk * B + b];
  __syncthreads();
  int e0 = blk * chunk, e1 = min(ne, e0 + chunk);
  for (int i = e0 + t; i < e1; i += 256) {
    int c = col[i];
    int pos = atomicAdd(&cur[c >> 8], 1);
    tmp[pos] = make_int2(row[i], c);
  }
}

__global__ __launch_bounds__(256)
void bucket_csr_kernel(const int2* __restrict__ tmp, const int* __restrict__ bs,
                       int* __restrict__ rowp, float* __restrict__ dis,
                       float* __restrict__ dinv, int* __restrict__ ep, int n) {
  __shared__ int h[256], lo[256], cur[256];
  int t = threadIdx.x, b = blockIdx.x;
  h[t] = 0;
  __syncthreads();
  int s0 = bs[b], s1 = bs[b + 1];
  for (int i = s0 + t; i < s1; i += 256)
    atomicAdd(&h[tmp[i].y & 255], 1);
  __syncthreads();
  if (t == 0) {
    int run = 0;
    for (int cb = 0; cb < 256; ++cb) { lo[cb] = run; run += h[cb]; }
  }
  __syncthreads();
  cur[t] = lo[t];
  int node = (b << 8) + t;
  if (node < n) {
    int c = h[t];
    rowp[node] = s0 + lo[t];
    float d = (float)(c + 1);
    dinv[node] = 1.0f / d;
    dis[node]  = rsqrtf(d);
    if (node == n - 1) rowp[n] = s1;
  }
  __syncthreads();
  for (int i = s0 + t; i < s1; i += 256) {
    int2 rc = tmp[i];
    int r = atomicAdd(&cur[rc.y & 255], 1);
    ep[s0 + r] = rc.x;
  }
}

template<int M>
__global__ __launch_bounds__(256)
void gemm_mfma_kernel(const _Float16* __restrict__ Xh,
                      const _Float16* __restrict__ Wt,
                      _Float16* __restrict__ Y, int N) {
  gemm_tile<M>(Xh, Wt, Y, N, blockIdx.x, threadIdx.x);
}

template<bool RELU>
__global__ __launch_bounds__(256)
void agg128h_kernel(const __half* __restrict__ xw, const int* __restrict__ row_ptr,
                    const int* __restrict__ ep, const float* __restrict__ dis,
                    const float* __restrict__ deg_inv, const float* __restrict__ bias,
                    __half* __restrict__ out, int n) {
  int wave = (blockIdx.x * 256 + threadIdx.x) >> 6;
  int lane = threadIdx.x & 63;
  if (wave >= n) return;
  agg128_body<RELU>(xw, row_ptr, ep, dis, deg_inv, bias, out, wave, lane);
}

template<bool RELU>
__global__ __launch_bounds__(256)
void agg64h_kernel(const __half* __restrict__ xw, const int* __restrict__ row_ptr,
                   const int* __restrict__ ep, const float* __restrict__ dis,
                   const float* __restrict__ deg_inv, const float* __restrict__ bias,
                   __half* __restrict__ out, int n) {
  int wave = (blockIdx.x * 256 + threadIdx.x) >> 6;
  int lane = threadIdx.x & 63;
  if (wave >= n) return;
  agg64_body<RELU>(xw, row_ptr, ep, dis, deg_inv, bias, out, wave, lane);
}

__global__ __launch_bounds__(256)
void decode_kernel(const __half* __restrict__ z, const int* __restrict__ eli,
                   float* __restrict__ out, int nl) {
  int wave = (blockIdx.x * 256 + threadIdx.x) >> 6;
  int lane = threadIdx.x & 63;
  if (wave >= nl) return;
  int src = eli[wave];
  int dst = eli[nl + wave];
  int node = (lane < 32) ? src : dst;
  int sub = lane & 31;
  float2 v = __half22float2(((const __half2*)(z + (size_t)node * 64))[sub]);
  float ox = __shfl_xor(v.x, 32, 64);
  float oy = __shfl_xor(v.y, 32, 64);
  float p = v.x * ox + v.y * oy;
#pragma unroll
  for (int m = 16; m >= 1; m >>= 1) p += __shfl_xor(p, m, 64);
  if (lane == 0) out[wave] = p;
}

// ---------------------------------------------------------------------------

extern "C" void kernel_launch(void* const* d_in, const int* in_sizes, int n_in,
                              void* d_out, int out_size, void* d_ws, size_t ws_size,
                              hipStream_t stream) {
  const float* x  = (const float*)d_in[0];
  const float* W1 = (const float*)d_in[1];
  const float* b1 = (const float*)d_in[2];
  const float* W2 = (const float*)d_in[3];
  const float* b2 = (const float*)d_in[4];
  const int* eidx = (const int*)d_in[5];
  const int* eli  = (const int*)d_in[6];
  const int N  = in_sizes[0] / 128;
  const int E  = in_sizes[5] / 2;
  const int NL = in_sizes[6] / 2;
  float* out = (float*)d_out;

  char* ws = (char*)d_ws;
  size_t off = 0;
  auto alloc = [&](size_t bytes) -> char* {
    char* p = ws + off;
    off = (off + bytes + 255) & ~(size_t)255;
    return p;
  };
  const int B = (N + 255) / 256;        // buckets (col>>8); needs N <= 65536
  float*    dis   = (float*)   alloc((size_t)N * 4);
  float*    dinv  = (float*)   alloc((size_t)N * 4);
  int*      rowp  = (int*)     alloc((size_t)(N + 1) * 4);
  int*      bhist = (int*)     alloc((size_t)GMAX * B * 4);
  int*      base  = (int*)     alloc((size_t)GMAX * B * 4);
  int*      bs    = (int*)     alloc((size_t)(B + 1) * 4);
  int*      tot   = (int*)     alloc((size_t)B * 4);
  int2*     tmp   = (int2*)    alloc((size_t)E * 8);
  int*      ep    = (int*)     alloc((size_t)E * 4);
  _Float16* Xh    = (_Float16*)alloc((size_t)N * 128 * 2);
  _Float16* W1t   = (_Float16*)alloc((size_t)128 * 128 * 2);
  _Float16* W2t   = (_Float16*)alloc((size_t)64 * 128 * 2);
  __half*   bufA  = (__half*)  alloc((size_t)N * 128 * 2);
  __half*   bufB  = (__half*)  alloc((size_t)N * 128 * 2);
  __half*   bufC  = (__half*)  alloc((size_t)N * 64 * 2);
  __half*   z     = (__half*)  alloc((size_t)N * 64 * 2);
  (void)ws_size; (void)n_in; (void)out_size;

  const int* row = eidx;      // edge_index[0]
  const int* col = eidx + E;  // edge_index[1]
  const int n4 = N * 32;      // N*128/4 float4 groups

  // -------- cooperative fused path --------
  static int s_grid = -1;
  if (s_grid < 0) {
    int nb = 0;
    hipError_t qe = hipOccupancyMaxActiveBlocksPerMultiprocessor(&nb, mega_kernel, 256, 0);
    if (qe != hipSuccess || nb < 1) nb = 0;
    long g = (long)nb * 256;   // 256 CUs on MI355X
    if (g > GMAX) g = GMAX;
    s_grid = (int)g;           // 0 => always use fallback
  }
  if (s_grid >= 256) {
    MegaArgs a;
    a.x = x; a.W1 = W1; a.b1 = b1; a.W2 = W2; a.b2 = b2;
    a.row = row; a.col = col; a.eli = eli; a.out = out;
    a.dis = dis; a.dinv = dinv; a.rowp = rowp;
    a.bhist = bhist; a.base = base; a.bs = bs; a.tot = tot;
    a.tmp = tmp; a.ep = ep;
    a.Xh = Xh; a.W1t = W1t; a.W2t = W2t;
    a.bufA = bufA; a.bufB = bufB; a.bufC = bufC; a.z = z;
    a.N = N; a.E = E; a.NL = NL; a.B = B; a.n4 = n4;
    a.cs = (E + s_grid - 1) / s_grid;
    void* kargs[] = { &a };
    hipError_t le = hipLaunchCooperativeKernel(mega_kernel, dim3(s_grid), dim3(256),
                                               kargs, 0, stream);
    if (le == hipSuccess) return;
    // clean failure -> fall through to classic path
  }

  // -------- fallback: round-14 ten-kernel pipeline --------
  const int chunk = (E + NBLK - 1) / NBLK;
  prep_kernel<<<(n4 + 255) / 256, 256, 0, stream>>>(x, W1, W2, Xh, W1t, W2t, n4);
  hist_kernel<<<NBLK, 256, 0, stream>>>(col, bhist, E, chunk, B);
  base_kernel<<<1, 256, 0, stream>>>(bhist, base, bs, B);
  bucket_scatter_kernel<<<NBLK, 256, 0, stream>>>(row, col, base, tmp, E, chunk, B);
  bucket_csr_kernel<<<B, 256, 0, stream>>>(tmp, bs, rowp, dis, dinv, ep, N);
  gemm_mfma_kernel<128><<<(N + 63) / 64, 256, 0, stream>>>(Xh, W1t, (_Float16*)bufA, N);
  agg128h_kernel<true><<<(N + 3) / 4, 256, 0, stream>>>(bufA, rowp, ep, dis, dinv, b1, bufB, N);
  gemm_mfma_kernel<64><<<(N + 63) / 64, 256, 0, stream>>>((const _Float16*)bufB, W2t,
                                                          (_Float16*)bufC, N);
  agg64h_kernel<false><<<(N + 3) / 4, 256, 0, stream>>>(bufC, rowp, ep, dis, dinv, b2, z, N);
  decode_kernel<<<(NL + 3) / 4, 256, 0, stream>>>(z, eli, out, NL);
}

// Round 2
// 251.528 us; speedup vs baseline: 3.4354x; 3.4354x over previous
//
#include <hip/hip_runtime.h>
#include <hip/hip_bf16.h>
#include <hip/hip_fp16.h>

// ---------------------------------------------------------------------------
// GCN link prediction (math fp32, fp16 tables, MFMA GEMMs).
// Round 16: revert the cooperative mega-kernel (grid.sync cost ~75-100us each
// at 1024 blocks across 8 XCDs -> 864us, 3.3x WORSE). Back to the verified
// round-14 10-kernel pipeline, minus two dispatch boundaries via sync-free
// fusion (dependencies already satisfied by stream order, parallelism kept):
//   k1 prep+hist   (blocks 0..255 histogram; all 2048 blocks grid-stride prep)
//   k2 base        (1 block)
//   k3 scatter     (256 blocks)
//   k4 csr+gemm1   (782 blocks; blocks<196 finalize CSR bucket, all do tiles)
//   k5 agg128+relu (12500 blocks — unchanged)
//   k6 gemm2       (782 blocks — unchanged)
//   k7 agg64       (12500 blocks — unchanged)
//   k8 decode      (50000 blocks — unchanged)
// ---------------------------------------------------------------------------

typedef _Float16 half8 __attribute__((ext_vector_type(8)));
typedef _Float16 half4v __attribute__((ext_vector_type(4)));
typedef float   floatx4 __attribute__((ext_vector_type(4)));

#define NBLK 256  // blocks for edge-chunk passes (hist/scatter chunking)

// ---------------------------------------------------------------------------
// Device bodies (verbatim round-14 logic)
// ---------------------------------------------------------------------------

template<int M>
__device__ __forceinline__ void gemm_tile(const _Float16* __restrict__ Xh,
                                          const _Float16* __restrict__ Wt,
                                          _Float16* __restrict__ Y,
                                          int N, int tile, int t) {
  constexpr int K = 128;
  constexpr int CT = M / 16;
  const int lane = t & 63;
  const int i16 = lane & 15;
  const int quad = lane >> 4;
  const int row0 = tile * 64 + (t >> 6) * 16;
  int arow = row0 + i16;
  if (arow >= N) arow = N - 1;
  const _Float16* aptr = Xh + (size_t)arow * K + quad * 8;
  floatx4 acc[CT];
#pragma unroll
  for (int c = 0; c < CT; ++c) acc[c] = (floatx4){0.f, 0.f, 0.f, 0.f};
#pragma unroll
  for (int k0 = 0; k0 < K; k0 += 32) {
    half8 a = *(const half8*)(aptr + k0);
#pragma unroll
    for (int c = 0; c < CT; ++c) {
      half8 b = *(const half8*)(Wt + (size_t)(c * 16 + i16) * K + quad * 8 + k0);
      acc[c] = __builtin_amdgcn_mfma_f32_16x16x32_f16(a, b, acc[c], 0, 0, 0);
    }
  }
#pragma unroll
  for (int c = 0; c < CT; ++c) {
#pragma unroll
    for (int r = 0; r < 4; ++r) {
      int gr = row0 + quad * 4 + r;
      if (gr < N) Y[(size_t)gr * M + c * 16 + i16] = (_Float16)acc[c][r];
    }
  }
}

// Broadcast edge j's (src, dis) with UNIFORM shfl indices; zero weight if
// j >= m (src clamped to edge k's — always valid).
#define BCAST(j, svar, dvar)                          \
  {                                                   \
    int jj = (j) < m ? (j) : k;                       \
    svar = __shfl(er, jj, 64);                        \
    dvar = ((j) < m) ? __shfl(dr, jj, 64) : 0.f;      \
  }

template<bool RELU>
__device__ __forceinline__ void agg128_body(
    const __half* __restrict__ xw, const int* __restrict__ row_ptr,
    const int* __restrict__ ep, const float* __restrict__ dis,
    const float* __restrict__ deg_inv, const float* __restrict__ bias,
    __half* __restrict__ out, int node, int lane) {
  const int s0 = row_ptr[node], s1 = row_ptr[node + 1];
  const int sub = lane & 15;
  const int quarter = lane >> 4;
  const float disc = dis[node];
  float a0[8], a1[8];
#pragma unroll
  for (int j = 0; j < 8; ++j) { a0[j] = 0.f; a1[j] = 0.f; }
  for (int base = s0; base < s1; base += 64) {
    int m = s1 - base; if (m > 64) m = 64;   // wave-uniform
    int er = 0; float dr = 0.f;
    if (lane < m) { er = ep[base + lane]; dr = dis[er]; }
    for (int k = 0; k < m; k += 8) {
      {
        int sA, sB, sC, sD; float dA, dB, dC, dD;
        BCAST(k,     sA, dA); BCAST(k + 1, sB, dB);
        BCAST(k + 2, sC, dC); BCAST(k + 3, sD, dD);
        int   s = (quarter == 0) ? sA : (quarter == 1) ? sB : (quarter == 2) ? sC : sD;
        float w = ((quarter == 0) ? dA : (quarter == 1) ? dB : (quarter == 2) ? dC : dD) * disc;
        float4 raw = ((const float4*)(xw + (size_t)s * 128))[sub];
        const __half2* hp = (const __half2*)&raw;
#pragma unroll
        for (int j = 0; j < 4; ++j) {
          float2 v = __half22float2(hp[j]);
          a0[2 * j]     = fmaf(w, v.x, a0[2 * j]);
          a0[2 * j + 1] = fmaf(w, v.y, a0[2 * j + 1]);
        }
      }
      if (k + 4 < m) {
        int sA, sB, sC, sD; float dA, dB, dC, dD;
        BCAST(k + 4, sA, dA); BCAST(k + 5, sB, dB);
        BCAST(k + 6, sC, dC); BCAST(k + 7, sD, dD);
        int   s = (quarter == 0) ? sA : (quarter == 1) ? sB : (quarter == 2) ? sC : sD;
        float w = ((quarter == 0) ? dA : (quarter == 1) ? dB : (quarter == 2) ? dC : dD) * disc;
        float4 raw = ((const float4*)(xw + (size_t)s * 128))[sub];
        const __half2* hp = (const __half2*)&raw;
#pragma unroll
        for (int j = 0; j < 4; ++j) {
          float2 v = __half22float2(hp[j]);
          a1[2 * j]     = fmaf(w, v.x, a1[2 * j]);
          a1[2 * j + 1] = fmaf(w, v.y, a1[2 * j + 1]);
        }
      }
    }
  }
#pragma unroll
  for (int j = 0; j < 8; ++j) {
    a0[j] += a1[j];
    a0[j] += __shfl_xor(a0[j], 16, 64);
    a0[j] += __shfl_xor(a0[j], 32, 64);
  }
  if (quarter == 0) {
    float di = deg_inv[node];
    float4 sraw = ((const float4*)(xw + (size_t)node * 128))[sub];
    const __half2* sp = (const __half2*)&sraw;
    const float4* bp = (const float4*)(bias + 8 * sub);
    float o[8];
#pragma unroll
    for (int j = 0; j < 4; ++j) {
      float2 sv = __half22float2(sp[j]);
      o[2 * j]     = a0[2 * j]     + sv.x * di;
      o[2 * j + 1] = a0[2 * j + 1] + sv.y * di;
    }
    float4 b0 = bp[0], b1v = bp[1];
    o[0] += b0.x; o[1] += b0.y; o[2] += b0.z; o[3] += b0.w;
    o[4] += b1v.x; o[5] += b1v.y; o[6] += b1v.z; o[7] += b1v.w;
    if (RELU) {
#pragma unroll
      for (int j = 0; j < 8; ++j) o[j] = fmaxf(o[j], 0.f);
    }
    __half2 h2[4];
#pragma unroll
    for (int j = 0; j < 4; ++j)
      h2[j] = __float22half2_rn(make_float2(o[2 * j], o[2 * j + 1]));
    *(float4*)(out + (size_t)node * 128 + 8 * sub) = *(const float4*)h2;
  }
}

template<bool RELU>
__device__ __forceinline__ void agg64_body(
    const __half* __restrict__ xw, const int* __restrict__ row_ptr,
    const int* __restrict__ ep, const float* __restrict__ dis,
    const float* __restrict__ deg_inv, const float* __restrict__ bias,
    __half* __restrict__ out, int node, int lane) {
  const int s0 = row_ptr[node], s1 = row_ptr[node + 1];
  const int sub = lane & 15;
  const int quarter = lane >> 4;
  const float disc = dis[node];
  float a0[4], a1[4];
#pragma unroll
  for (int j = 0; j < 4; ++j) { a0[j] = 0.f; a1[j] = 0.f; }
  for (int base = s0; base < s1; base += 64) {
    int m = s1 - base; if (m > 64) m = 64;
    int er = 0; float dr = 0.f;
    if (lane < m) { er = ep[base + lane]; dr = dis[er]; }
    for (int k = 0; k < m; k += 8) {
      {
        int sA, sB, sC, sD; float dA, dB, dC, dD;
        BCAST(k,     sA, dA); BCAST(k + 1, sB, dB);
        BCAST(k + 2, sC, dC); BCAST(k + 3, sD, dD);
        int   s = (quarter == 0) ? sA : (quarter == 1) ? sB : (quarter == 2) ? sC : sD;
        float w = ((quarter == 0) ? dA : (quarter == 1) ? dB : (quarter == 2) ? dC : dD) * disc;
        float2 raw = ((const float2*)(xw + (size_t)s * 64))[sub];
        const __half2* hp = (const __half2*)&raw;
#pragma unroll
        for (int j = 0; j < 2; ++j) {
          float2 v = __half22float2(hp[j]);
          a0[2 * j]     = fmaf(w, v.x, a0[2 * j]);
          a0[2 * j + 1] = fmaf(w, v.y, a0[2 * j + 1]);
        }
      }
      if (k + 4 < m) {
        int sA, sB, sC, sD; float dA, dB, dC, dD;
        BCAST(k + 4, sA, dA); BCAST(k + 5, sB, dB);
        BCAST(k + 6, sC, dC); BCAST(k + 7, sD, dD);
        int   s = (quarter == 0) ? sA : (quarter == 1) ? sB : (quarter == 2) ? sC : sD;
        float w = ((quarter == 0) ? dA : (quarter == 1) ? dB : (quarter == 2) ? dC : dD) * disc;
        float2 raw = ((const float2*)(xw + (size_t)s * 64))[sub];
        const __half2* hp = (const __half2*)&raw;
#pragma unroll
        for (int j = 0; j < 2; ++j) {
          float2 v = __half22float2(hp[j]);
          a1[2 * j]     = fmaf(w, v.x, a1[2 * j]);
          a1[2 * j + 1] = fmaf(w, v.y, a1[2 * j + 1]);
        }
      }
    }
  }
#pragma unroll
  for (int j = 0; j < 4; ++j) {
    a0[j] += a1[j];
    a0[j] += __shfl_xor(a0[j], 16, 64);
    a0[j] += __shfl_xor(a0[j], 32, 64);
  }
  if (quarter == 0) {
    float di = deg_inv[node];
    float2 sraw = ((const float2*)(xw + (size_t)node * 64))[sub];
    const __half2* sp = (const __half2*)&sraw;
    float4 bv = ((const float4*)(bias))[sub];
    float2 s0v = __half22float2(sp[0]);
    float2 s1v = __half22float2(sp[1]);
    float o0 = a0[0] + s0v.x * di + bv.x;
    float o1 = a0[1] + s0v.y * di + bv.y;
    float o2 = a0[2] + s1v.x * di + bv.z;
    float o3 = a0[3] + s1v.y * di + bv.w;
    if (RELU) {
      o0 = fmaxf(o0, 0.f); o1 = fmaxf(o1, 0.f);
      o2 = fmaxf(o2, 0.f); o3 = fmaxf(o3, 0.f);
    }
    __half2 h2[2];
    h2[0] = __float22half2_rn(make_float2(o0, o1));
    h2[1] = __float22half2_rn(make_float2(o2, o3));
    *(float2*)(out + (size_t)node * 64 + 4 * sub) = *(const float2*)h2;
  }
}

// ---------------------------------------------------------------------------
// k1: fused prep + per-chunk bucket histogram.
// Blocks 0..NBLK-1 histogram their edge chunk (LDS atomics, as round-14);
// ALL blocks then grid-stride the x->fp16 conversion + W transposes.
// No inter-phase dependency: hist consumes col, prep consumes x/W1/W2.
// ---------------------------------------------------------------------------
__global__ __launch_bounds__(256)
void prep_hist_kernel(const float* __restrict__ x, const float* __restrict__ W1,
                      const float* __restrict__ W2, _Float16* __restrict__ Xh,
                      _Float16* __restrict__ W1t, _Float16* __restrict__ W2t,
                      int n4, const int* __restrict__ col,
                      int* __restrict__ bhist, int ne, int chunk, int B) {
  int t = threadIdx.x, blk = blockIdx.x;
  if (blk < NBLK) {   // histogram part (same parallelism as round-14 hist)
    __shared__ int h[256];
    for (int b = t; b < B; b += 256) h[b] = 0;
    __syncthreads();
    int e0 = blk * chunk, e1 = min(ne, e0 + chunk);
    for (int i = e0 + t; i < e1; i += 256)
      atomicAdd(&h[col[i] >> 8], 1);
    __syncthreads();
    for (int b = t; b < B; b += 256) bhist[blk * B + b] = h[b];
  }
  // prep part: all blocks
  const int gs = gridDim.x * 256;
  for (int i = blk * 256 + t; i < n4; i += gs) {
    float4 v = ((const float4*)x)[i];
    half4v h4; h4[0] = (_Float16)v.x; h4[1] = (_Float16)v.y;
    h4[2] = (_Float16)v.z; h4[3] = (_Float16)v.w;
    ((half4v*)Xh)[i] = h4;
    if (i < 128 * 128) { int k = i >> 7, n = i & 127; W1t[(size_t)n * 128 + k] = (_Float16)W1[i]; }
    if (i < 128 * 64)  { int k = i >> 6, n = i & 63;  W2t[(size_t)n * 128 + k] = (_Float16)W2[i]; }
  }
}

// k2: bucket totals, bucket starts bs[0..B], per-block bases (1 block).
__global__ __launch_bounds__(256)
void base_kernel(const int* __restrict__ bhist, int* __restrict__ base,
                 int* __restrict__ bs, int B) {
  __shared__ int tot[256];
  __shared__ int start[257];
  int t = threadIdx.x;
  if (t < B) {
    int s = 0;
    for (int blk = 0; blk < NBLK; ++blk) s += bhist[blk * B + t];
    tot[t] = s;
  }
  __syncthreads();
  if (t == 0) {
    int run = 0;
    for (int b = 0; b < B; ++b) { start[b] = run; run += tot[b]; }
    start[B] = run;
  }
  __syncthreads();
  if (t <= B) bs[t] = start[t];
  if (t < B) {
    int run = start[t];
    for (int blk = 0; blk < NBLK; ++blk) {
      base[blk * B + t] = run;
      run += bhist[blk * B + t];
    }
  }
}

// k3: scatter edges into bucket-grouped tmp[(r,c)] via LDS cursors.
__global__ __launch_bounds__(256)
void bucket_scatter_kernel(const int* __restrict__ row, const int* __restrict__ col,
                           const int* __restrict__ base, int2* __restrict__ tmp,
                           int ne, int chunk, int B) {
  __shared__ int cur[256];
  int t = threadIdx.x, blk = blockIdx.x;
  for (int b = t; b < B; b += 256) cur[b] = base[blk * B + b];
  __syncthreads();
  int e0 = blk * chunk, e1 = min(ne, e0 + chunk);
  for (int i = e0 + t; i < e1; i += 256) {
    int c = col[i];
    int pos = atomicAdd(&cur[c >> 8], 1);
    tmp[pos] = make_int2(row[i], c);
  }
}

// ---------------------------------------------------------------------------
// k4: fused per-bucket CSR finalize + gemm1.
// Grid = TG (gemm1 tiles) >= B (buckets). Blocks < B first finalize their CSR
// bucket (round-14 body), then every block computes its 64-row gemm1 tile.
// gemm1 depends only on k1 (Xh/W1t, stream order); csr only on k3 (tmp).
// No intra-kernel dependency between the two parts.
// ---------------------------------------------------------------------------
__global__ __launch_bounds__(256)
void csr_gemm1_kernel(const int2* __restrict__ tmp, const int* __restrict__ bs,
                      int* __restrict__ rowp, float* __restrict__ dis,
                      float* __restrict__ dinv, int* __restrict__ ep, int n, int B,
                      const _Float16* __restrict__ Xh, const _Float16* __restrict__ W1t,
                      _Float16* __restrict__ Y) {
  int t = threadIdx.x, b = blockIdx.x;
  if (b < B) {
    __shared__ int h[256], lo[256], cur[256];
    h[t] = 0;
    __syncthreads();
    int s0 = bs[b], s1 = bs[b + 1];
    for (int i = s0 + t; i < s1; i += 256)
      atomicAdd(&h[tmp[i].y & 255], 1);
    __syncthreads();
    if (t == 0) {
      int run = 0;
      for (int cb = 0; cb < 256; ++cb) { lo[cb] = run; run += h[cb]; }
    }
    __syncthreads();
    cur[t] = lo[t];
    int node = (b << 8) + t;
    if (node < n) {
      int c = h[t];
      rowp[node] = s0 + lo[t];
      float d = (float)(c + 1);   // +1 self loop
      dinv[node] = 1.0f / d;
      dis[node]  = rsqrtf(d);
      if (node == n - 1) rowp[n] = s1;   // last bucket end == E
    }
    __syncthreads();
    for (int i = s0 + t; i < s1; i += 256) {
      int2 rc = tmp[i];
      int r = atomicAdd(&cur[rc.y & 255], 1);
      ep[s0 + r] = rc.x;
    }
  }
  // gemm1 tile for this block (CSR outputs are not consumed here)
  gemm_tile<128>(Xh, W1t, Y, n, b, t);
}

// k6: standalone gemm2.
template<int M>
__global__ __launch_bounds__(256)
void gemm_mfma_kernel(const _Float16* __restrict__ Xh,
                      const _Float16* __restrict__ Wt,
                      _Float16* __restrict__ Y, int N) {
  gemm_tile<M>(Xh, Wt, Y, N, blockIdx.x, threadIdx.x);
}

// k5 / k7: aggregation wrappers (round-14 grids: 1 wave per node).
template<bool RELU>
__global__ __launch_bounds__(256)
void agg128h_kernel(const __half* __restrict__ xw, const int* __restrict__ row_ptr,
                    const int* __restrict__ ep, const float* __restrict__ dis,
                    const float* __restrict__ deg_inv, const float* __restrict__ bias,
                    __half* __restrict__ out, int n) {
  int wave = (blockIdx.x * 256 + threadIdx.x) >> 6;
  int lane = threadIdx.x & 63;
  if (wave >= n) return;
  agg128_body<RELU>(xw, row_ptr, ep, dis, deg_inv, bias, out, wave, lane);
}

template<bool RELU>
__global__ __launch_bounds__(256)
void agg64h_kernel(const __half* __restrict__ xw, const int* __restrict__ row_ptr,
                   const int* __restrict__ ep, const float* __restrict__ dis,
                   const float* __restrict__ deg_inv, const float* __restrict__ bias,
                   __half* __restrict__ out, int n) {
  int wave = (blockIdx.x * 256 + threadIdx.x) >> 6;
  int lane = threadIdx.x & 63;
  if (wave >= n) return;
  agg64_body<RELU>(xw, row_ptr, ep, dis, deg_inv, bias, out, wave, lane);
}

// k8: decode — half-wave src/dst split.
__global__ __launch_bounds__(256)
void decode_kernel(const __half* __restrict__ z, const int* __restrict__ eli,
                   float* __restrict__ out, int nl) {
  int wave = (blockIdx.x * 256 + threadIdx.x) >> 6;
  int lane = threadIdx.x & 63;
  if (wave >= nl) return;
  int src = eli[wave];
  int dst = eli[nl + wave];
  int node = (lane < 32) ? src : dst;
  int sub = lane & 31;
  float2 v = __half22float2(((const __half2*)(z + (size_t)node * 64))[sub]);
  float ox = __shfl_xor(v.x, 32, 64);
  float oy = __shfl_xor(v.y, 32, 64);
  float p = v.x * ox + v.y * oy;
#pragma unroll
  for (int m = 16; m >= 1; m >>= 1) p += __shfl_xor(p, m, 64);
  if (lane == 0) out[wave] = p;
}

// ---------------------------------------------------------------------------

extern "C" void kernel_launch(void* const* d_in, const int* in_sizes, int n_in,
                              void* d_out, int out_size, void* d_ws, size_t ws_size,
                              hipStream_t stream) {
  const float* x  = (const float*)d_in[0];
  const float* W1 = (const float*)d_in[1];
  const float* b1 = (const float*)d_in[2];
  const float* W2 = (const float*)d_in[3];
  const float* b2 = (const float*)d_in[4];
  const int* eidx = (const int*)d_in[5];
  const int* eli  = (const int*)d_in[6];
  const int N  = in_sizes[0] / 128;
  const int E  = in_sizes[5] / 2;
  const int NL = in_sizes[6] / 2;
  float* out = (float*)d_out;

  char* ws = (char*)d_ws;
  size_t off = 0;
  auto alloc = [&](size_t bytes) -> char* {
    char* p = ws + off;
    off = (off + bytes + 255) & ~(size_t)255;
    return p;
  };
  const int B = (N + 255) / 256;        // buckets (col>>8); needs N <= 65536
  const int chunk = (E + NBLK - 1) / NBLK;
  float*    dis   = (float*)   alloc((size_t)N * 4);
  float*    dinv  = (float*)   alloc((size_t)N * 4);
  int*      rowp  = (int*)     alloc((size_t)(N + 1) * 4);
  int*      bhist = (int*)     alloc((size_t)NBLK * B * 4);
  int*      base  = (int*)     alloc((size_t)NBLK * B * 4);
  int*      bs    = (int*)     alloc((size_t)(B + 1) * 4);
  int2*     tmp   = (int2*)    alloc((size_t)E * 8);
  int*      ep    = (int*)     alloc((size_t)E * 4);
  _Float16* Xh    = (_Float16*)alloc((size_t)N * 128 * 2);
  _Float16* W1t   = (_Float16*)alloc((size_t)128 * 128 * 2);
  _Float16* W2t   = (_Float16*)alloc((size_t)64 * 128 * 2);
  __half*   bufA  = (__half*)  alloc((size_t)N * 128 * 2);
  __half*   bufB  = (__half*)  alloc((size_t)N * 128 * 2);
  __half*   bufC  = (__half*)  alloc((size_t)N * 64 * 2);
  __half*   z     = (__half*)  alloc((size_t)N * 64 * 2);
  (void)ws_size; (void)n_in; (void)out_size;

  const int* row = eidx;      // edge_index[0]
  const int* col = eidx + E;  // edge_index[1]
  const int n4 = N * 32;      // N*128/4 float4 groups
  const int TG = (N + 63) / 64;  // gemm tiles (782) >= B (196)

  // k1: prep + hist fused (2048 blocks: 256 hist chunks + grid-stride prep)
  prep_hist_kernel<<<2048, 256, 0, stream>>>(x, W1, W2, Xh, W1t, W2t, n4,
                                             col, bhist, E, chunk, B);
  // k2: bucket bases (1 block)
  base_kernel<<<1, 256, 0, stream>>>(bhist, base, bs, B);
  // k3: scatter into bucket-grouped tmp
  bucket_scatter_kernel<<<NBLK, 256, 0, stream>>>(row, col, base, tmp, E, chunk, B);
  // k4: CSR finalize + gemm1 fused (bufA = half(Xh@W1))
  csr_gemm1_kernel<<<TG, 256, 0, stream>>>(tmp, bs, rowp, dis, dinv, ep, N, B,
                                           Xh, W1t, (_Float16*)bufA);
  // k5: bufB = half(relu(agg(bufA)+dinv*bufA+b1))
  agg128h_kernel<true><<<(N + 3) / 4, 256, 0, stream>>>(bufA, rowp, ep, dis, dinv, b1, bufB, N);
  // k6: bufC = half(bufB@W2)
  gemm_mfma_kernel<64><<<TG, 256, 0, stream>>>((const _Float16*)bufB, W2t,
                                               (_Float16*)bufC, N);
  // k7: z = half(agg(bufC)+dinv*bufC+b2)
  agg64h_kernel<false><<<(N + 3) / 4, 256, 0, stream>>>(bufC, rowp, ep, dis, dinv, b2, z, N);
  // k8: decode
  decode_kernel<<<(NL + 3) / 4, 256, 0, stream>>>(z, eli, out, NL);
}

// Round 3
// 247.005 us; speedup vs baseline: 3.4983x; 1.0183x over previous
//
#include <hip/hip_runtime.h>
#include <hip/hip_bf16.h>
#include <hip/hip_fp16.h>

// ---------------------------------------------------------------------------
// GCN link prediction (math fp32, fp16 tables, MFMA GEMMs).
// Round 17: 7 dispatches.
//  - aggs: direct per-quarter/oct uniform loads of (src, w) replace the
//    shuffle-broadcast scheme (16 ds_bpermute + 12 cndmask per 8 edges -> 4
//    loads); agg128 caches wt[e]=dis[src] for agg64 (no random dis gather in
//    pass 2); agg64 widened to 8-edge oct parallelism.
//  - base_kernel fused into scatter (each block recomputes bucket prefix from
//    L2-resident bhist; block 0 publishes bs). -1 dispatch.
//   k1 prep+hist   (2048 blocks)
//   k2 scatter+base(256 blocks)
//   k3 csr+gemm1   (782 blocks)
//   k4 agg128+relu (12500 blocks)
//   k5 gemm2       (782 blocks)
//   k6 agg64       (12500 blocks)
//   k7 decode      (50000 blocks)
// ---------------------------------------------------------------------------

typedef _Float16 half8 __attribute__((ext_vector_type(8)));
typedef _Float16 half4v __attribute__((ext_vector_type(4)));
typedef float   floatx4 __attribute__((ext_vector_type(4)));

#define NBLK 256  // blocks for edge-chunk passes (hist/scatter chunking)

// ---------------------------------------------------------------------------

template<int M>
__device__ __forceinline__ void gemm_tile(const _Float16* __restrict__ Xh,
                                          const _Float16* __restrict__ Wt,
                                          _Float16* __restrict__ Y,
                                          int N, int tile, int t) {
  constexpr int K = 128;
  constexpr int CT = M / 16;
  const int lane = t & 63;
  const int i16 = lane & 15;
  const int quad = lane >> 4;
  const int row0 = tile * 64 + (t >> 6) * 16;
  int arow = row0 + i16;
  if (arow >= N) arow = N - 1;
  const _Float16* aptr = Xh + (size_t)arow * K + quad * 8;
  floatx4 acc[CT];
#pragma unroll
  for (int c = 0; c < CT; ++c) acc[c] = (floatx4){0.f, 0.f, 0.f, 0.f};
#pragma unroll
  for (int k0 = 0; k0 < K; k0 += 32) {
    half8 a = *(const half8*)(aptr + k0);
#pragma unroll
    for (int c = 0; c < CT; ++c) {
      half8 b = *(const half8*)(Wt + (size_t)(c * 16 + i16) * K + quad * 8 + k0);
      acc[c] = __builtin_amdgcn_mfma_f32_16x16x32_f16(a, b, acc[c], 0, 0, 0);
    }
  }
#pragma unroll
  for (int c = 0; c < CT; ++c) {
#pragma unroll
    for (int r = 0; r < 4; ++r) {
      int gr = row0 + quad * 4 + r;
      if (gr < N) Y[(size_t)gr * M + c * 16 + i16] = (_Float16)acc[c][r];
    }
  }
}

// ---------------------------------------------------------------------------
// k1: fused prep + per-chunk bucket histogram.
// ---------------------------------------------------------------------------
__global__ __launch_bounds__(256)
void prep_hist_kernel(const float* __restrict__ x, const float* __restrict__ W1,
                      const float* __restrict__ W2, _Float16* __restrict__ Xh,
                      _Float16* __restrict__ W1t, _Float16* __restrict__ W2t,
                      int n4, const int* __restrict__ col,
                      int* __restrict__ bhist, int ne, int chunk, int B) {
  int t = threadIdx.x, blk = blockIdx.x;
  if (blk < NBLK) {   // histogram part
    __shared__ int h[256];
    for (int b = t; b < B; b += 256) h[b] = 0;
    __syncthreads();
    int e0 = blk * chunk, e1 = min(ne, e0 + chunk);
    for (int i = e0 + t; i < e1; i += 256)
      atomicAdd(&h[col[i] >> 8], 1);
    __syncthreads();
    for (int b = t; b < B; b += 256) bhist[blk * B + b] = h[b];
  }
  // prep part: all blocks grid-stride
  const int gs = gridDim.x * 256;
  for (int i = blk * 256 + t; i < n4; i += gs) {
    float4 v = ((const float4*)x)[i];
    half4v h4; h4[0] = (_Float16)v.x; h4[1] = (_Float16)v.y;
    h4[2] = (_Float16)v.z; h4[3] = (_Float16)v.w;
    ((half4v*)Xh)[i] = h4;
    if (i < 128 * 128) { int k = i >> 7, n = i & 127; W1t[(size_t)n * 128 + k] = (_Float16)W1[i]; }
    if (i < 128 * 64)  { int k = i >> 6, n = i & 63;  W2t[(size_t)n * 128 + k] = (_Float16)W2[i]; }
  }
}

// ---------------------------------------------------------------------------
// k2: scatter with base computation fused (each block redundantly computes the
// bucket-prefix from L2-resident bhist; ~256 coalesced loads/thread + one
// serial 196-scan per block, all 256 blocks in parallel). Block 0 publishes
// bs[0..B] for k3.
// ---------------------------------------------------------------------------
__global__ __launch_bounds__(256)
void scatter_base_kernel(const int* __restrict__ row, const int* __restrict__ col,
                         const int* __restrict__ bhist, int2* __restrict__ tmp,
                         int* __restrict__ bs, int ne, int chunk, int B) {
  __shared__ int tot[256], my[256], start[257];
  int t = threadIdx.x, blk = blockIdx.x;
  if (t < B) {
    int s = 0, sp = 0;
    for (int b2 = 0; b2 < NBLK; ++b2) {
      int v = bhist[b2 * B + t];
      s += v;
      if (b2 < blk) sp += v;
    }
    tot[t] = s; my[t] = sp;
  }
  __syncthreads();
  if (t == 0) {
    int run = 0;
    for (int b = 0; b < B; ++b) { start[b] = run; run += tot[b]; }
    start[B] = run;
  }
  __syncthreads();
  if (blk == 0 && t <= B) bs[t] = start[t];
  if (t < B) tot[t] = start[t] + my[t];   // reuse tot[] as this block's cursors
  __syncthreads();
  int e0 = blk * chunk, e1 = min(ne, e0 + chunk);
  for (int i = e0 + t; i < e1; i += 256) {
    int c = col[i];
    int pos = atomicAdd(&tot[c >> 8], 1);
    tmp[pos] = make_int2(row[i], c);
  }
}

// ---------------------------------------------------------------------------
// k3: fused per-bucket CSR finalize + gemm1 (unchanged, passing).
// ---------------------------------------------------------------------------
__global__ __launch_bounds__(256)
void csr_gemm1_kernel(const int2* __restrict__ tmp, const int* __restrict__ bs,
                      int* __restrict__ rowp, float* __restrict__ dis,
                      float* __restrict__ dinv, int* __restrict__ ep, int n, int B,
                      const _Float16* __restrict__ Xh, const _Float16* __restrict__ W1t,
                      _Float16* __restrict__ Y) {
  int t = threadIdx.x, b = blockIdx.x;
  if (b < B) {
    __shared__ int h[256], lo[256], cur[256];
    h[t] = 0;
    __syncthreads();
    int s0 = bs[b], s1 = bs[b + 1];
    for (int i = s0 + t; i < s1; i += 256)
      atomicAdd(&h[tmp[i].y & 255], 1);
    __syncthreads();
    if (t == 0) {
      int run = 0;
      for (int cb = 0; cb < 256; ++cb) { lo[cb] = run; run += h[cb]; }
    }
    __syncthreads();
    cur[t] = lo[t];
    int node = (b << 8) + t;
    if (node < n) {
      int c = h[t];
      rowp[node] = s0 + lo[t];
      float d = (float)(c + 1);   // +1 self loop
      dinv[node] = 1.0f / d;
      dis[node]  = rsqrtf(d);
      if (node == n - 1) rowp[n] = s1;   // last bucket end == E
    }
    __syncthreads();
    for (int i = s0 + t; i < s1; i += 256) {
      int2 rc = tmp[i];
      int r = atomicAdd(&cur[rc.y & 255], 1);
      ep[s0 + r] = rc.x;
    }
  }
  gemm_tile<128>(Xh, W1t, Y, n, b, t);
}

// ---------------------------------------------------------------------------
// k4: CH=128 aggregation, direct-load quarter scheme.
// Quarter q handles edge e+q (group A) and e+4+q (group B). (src, dis[src])
// loaded directly with quarter-uniform addresses (consecutive edges -> one
// small L1/L2 fetch); no shuffle broadcasts. Also caches wt[e] = dis[src]
// for the second aggregation pass.
// ---------------------------------------------------------------------------
template<bool RELU>
__global__ __launch_bounds__(256)
void agg128h_kernel(const __half* __restrict__ xw, const int* __restrict__ row_ptr,
                    const int* __restrict__ ep, const float* __restrict__ dis,
                    float* __restrict__ wt, const float* __restrict__ deg_inv,
                    const float* __restrict__ bias, __half* __restrict__ out, int n) {
  int wave = (blockIdx.x * 256 + threadIdx.x) >> 6;
  int lane = threadIdx.x & 63;
  if (wave >= n) return;
  const int node = wave;
  const int s0 = row_ptr[node], s1 = row_ptr[node + 1];
  const int sub = lane & 15;
  const int q = lane >> 4;
  const float disc = dis[node];
  float a0[8], a1[8];
#pragma unroll
  for (int j = 0; j < 8; ++j) { a0[j] = 0.f; a1[j] = 0.f; }
  for (int e = s0; e < s1; e += 8) {
    int eA = e + q;
    int cA = min(eA, s1 - 1);
    int sA = ep[cA];
    float dA = dis[sA];
    float4 rawA = ((const float4*)(xw + (size_t)sA * 128))[sub];
    if (sub == 0 && eA < s1) wt[eA] = dA;
    float wA = (eA < s1) ? dA * disc : 0.f;
    const __half2* hpA = (const __half2*)&rawA;
#pragma unroll
    for (int j = 0; j < 4; ++j) {
      float2 v = __half22float2(hpA[j]);
      a0[2 * j]     = fmaf(wA, v.x, a0[2 * j]);
      a0[2 * j + 1] = fmaf(wA, v.y, a0[2 * j + 1]);
    }
    if (e + 4 < s1) {
      int eB = e + 4 + q;
      int cB = min(eB, s1 - 1);
      int sB = ep[cB];
      float dB = dis[sB];
      float4 rawB = ((const float4*)(xw + (size_t)sB * 128))[sub];
      if (sub == 0 && eB < s1) wt[eB] = dB;
      float wB = (eB < s1) ? dB * disc : 0.f;
      const __half2* hpB = (const __half2*)&rawB;
#pragma unroll
      for (int j = 0; j < 4; ++j) {
        float2 v = __half22float2(hpB[j]);
        a1[2 * j]     = fmaf(wB, v.x, a1[2 * j]);
        a1[2 * j + 1] = fmaf(wB, v.y, a1[2 * j + 1]);
      }
    }
  }
#pragma unroll
  for (int j = 0; j < 8; ++j) {
    a0[j] += a1[j];
    a0[j] += __shfl_xor(a0[j], 16, 64);
    a0[j] += __shfl_xor(a0[j], 32, 64);
  }
  if (q == 0) {
    float di = deg_inv[node];
    float4 sraw = ((const float4*)(xw + (size_t)node * 128))[sub];
    const __half2* sp = (const __half2*)&sraw;
    const float4* bp = (const float4*)(bias + 8 * sub);
    float o[8];
#pragma unroll
    for (int j = 0; j < 4; ++j) {
      float2 sv = __half22float2(sp[j]);
      o[2 * j]     = a0[2 * j]     + sv.x * di;
      o[2 * j + 1] = a0[2 * j + 1] + sv.y * di;
    }
    float4 b0 = bp[0], b1v = bp[1];
    o[0] += b0.x; o[1] += b0.y; o[2] += b0.z; o[3] += b0.w;
    o[4] += b1v.x; o[5] += b1v.y; o[6] += b1v.z; o[7] += b1v.w;
    if (RELU) {
#pragma unroll
      for (int j = 0; j < 8; ++j) o[j] = fmaxf(o[j], 0.f);
    }
    __half2 h2[4];
#pragma unroll
    for (int j = 0; j < 4; ++j)
      h2[j] = __float22half2_rn(make_float2(o[2 * j], o[2 * j + 1]));
    *(float4*)(out + (size_t)node * 128 + 8 * sub) = *(const float4*)h2;
  }
}

// ---------------------------------------------------------------------------
// k6: CH=64 aggregation, direct-load OCT scheme (8 edges in flight; 8 lanes x
// 16B = full 128B row per oct). Weight read coalesced from wt[] (cached by
// agg128) — no random dis gather in this pass.
// ---------------------------------------------------------------------------
template<bool RELU>
__global__ __launch_bounds__(256)
void agg64h_kernel(const __half* __restrict__ xw, const int* __restrict__ row_ptr,
                   const int* __restrict__ ep, const float* __restrict__ wt,
                   const float* __restrict__ dis, const float* __restrict__ deg_inv,
                   const float* __restrict__ bias, __half* __restrict__ out, int n) {
  int wave = (blockIdx.x * 256 + threadIdx.x) >> 6;
  int lane = threadIdx.x & 63;
  if (wave >= n) return;
  const int node = wave;
  const int s0 = row_ptr[node], s1 = row_ptr[node + 1];
  const int sub = lane & 7;       // 8 lanes x 16B = 128B row (8 ch each)
  const int oct = lane >> 3;      // 8 edges in flight
  const float disc = dis[node];
  float a0[8], a1[8];
#pragma unroll
  for (int j = 0; j < 8; ++j) { a0[j] = 0.f; a1[j] = 0.f; }
  for (int e = s0; e < s1; e += 16) {
    int eA = e + oct;
    int cA = min(eA, s1 - 1);
    int sA = ep[cA];
    float wA = (eA < s1) ? wt[cA] * disc : 0.f;
    float4 rawA = ((const float4*)(xw + (size_t)sA * 64))[sub];
    const __half2* hpA = (const __half2*)&rawA;
#pragma unroll
    for (int j = 0; j < 4; ++j) {
      float2 v = __half22float2(hpA[j]);
      a0[2 * j]     = fmaf(wA, v.x, a0[2 * j]);
      a0[2 * j + 1] = fmaf(wA, v.y, a0[2 * j + 1]);
    }
    if (e + 8 < s1) {
      int eB = e + 8 + oct;
      int cB = min(eB, s1 - 1);
      int sB = ep[cB];
      float wB = (eB < s1) ? wt[cB] * disc : 0.f;
      float4 rawB = ((const float4*)(xw + (size_t)sB * 64))[sub];
      const __half2* hpB = (const __half2*)&rawB;
#pragma unroll
      for (int j = 0; j < 4; ++j) {
        float2 v = __half22float2(hpB[j]);
        a1[2 * j]     = fmaf(wB, v.x, a1[2 * j]);
        a1[2 * j + 1] = fmaf(wB, v.y, a1[2 * j + 1]);
      }
    }
  }
#pragma unroll
  for (int j = 0; j < 8; ++j) {
    a0[j] += a1[j];
    a0[j] += __shfl_xor(a0[j], 8, 64);
    a0[j] += __shfl_xor(a0[j], 16, 64);
    a0[j] += __shfl_xor(a0[j], 32, 64);
  }
  if (oct == 0) {
    float di = deg_inv[node];
    float4 sraw = ((const float4*)(xw + (size_t)node * 64))[sub];
    const __half2* sp = (const __half2*)&sraw;
    const float4* bp = (const float4*)(bias + 8 * sub);
    float o[8];
#pragma unroll
    for (int j = 0; j < 4; ++j) {
      float2 sv = __half22float2(sp[j]);
      o[2 * j]     = a0[2 * j]     + sv.x * di;
      o[2 * j + 1] = a0[2 * j + 1] + sv.y * di;
    }
    float4 b0 = bp[0], b1v = bp[1];
    o[0] += b0.x; o[1] += b0.y; o[2] += b0.z; o[3] += b0.w;
    o[4] += b1v.x; o[5] += b1v.y; o[6] += b1v.z; o[7] += b1v.w;
    if (RELU) {
#pragma unroll
      for (int j = 0; j < 8; ++j) o[j] = fmaxf(o[j], 0.f);
    }
    __half2 h2[4];
#pragma unroll
    for (int j = 0; j < 4; ++j)
      h2[j] = __float22half2_rn(make_float2(o[2 * j], o[2 * j + 1]));
    *(float4*)(out + (size_t)node * 64 + 8 * sub) = *(const float4*)h2;
  }
}

// k5: standalone gemm2.
template<int M>
__global__ __launch_bounds__(256)
void gemm_mfma_kernel(const _Float16* __restrict__ Xh,
                      const _Float16* __restrict__ Wt,
                      _Float16* __restrict__ Y, int N) {
  gemm_tile<M>(Xh, Wt, Y, N, blockIdx.x, threadIdx.x);
}

// k7: decode — half-wave src/dst split (unchanged, passing).
__global__ __launch_bounds__(256)
void decode_kernel(const __half* __restrict__ z, const int* __restrict__ eli,
                   float* __restrict__ out, int nl) {
  int wave = (blockIdx.x * 256 + threadIdx.x) >> 6;
  int lane = threadIdx.x & 63;
  if (wave >= nl) return;
  int src = eli[wave];
  int dst = eli[nl + wave];
  int node = (lane < 32) ? src : dst;
  int sub = lane & 31;
  float2 v = __half22float2(((const __half2*)(z + (size_t)node * 64))[sub]);
  float ox = __shfl_xor(v.x, 32, 64);
  float oy = __shfl_xor(v.y, 32, 64);
  float p = v.x * ox + v.y * oy;
#pragma unroll
  for (int m = 16; m >= 1; m >>= 1) p += __shfl_xor(p, m, 64);
  if (lane == 0) out[wave] = p;
}

// ---------------------------------------------------------------------------

extern "C" void kernel_launch(void* const* d_in, const int* in_sizes, int n_in,
                              void* d_out, int out_size, void* d_ws, size_t ws_size,
                              hipStream_t stream) {
  const float* x  = (const float*)d_in[0];
  const float* W1 = (const float*)d_in[1];
  const float* b1 = (const float*)d_in[2];
  const float* W2 = (const float*)d_in[3];
  const float* b2 = (const float*)d_in[4];
  const int* eidx = (const int*)d_in[5];
  const int* eli  = (const int*)d_in[6];
  const int N  = in_sizes[0] / 128;
  const int E  = in_sizes[5] / 2;
  const int NL = in_sizes[6] / 2;
  float* out = (float*)d_out;

  char* ws = (char*)d_ws;
  size_t off = 0;
  auto alloc = [&](size_t bytes) -> char* {
    char* p = ws + off;
    off = (off + bytes + 255) & ~(size_t)255;
    return p;
  };
  const int B = (N + 255) / 256;        // buckets (col>>8); needs N <= 65536
  const int chunk = (E + NBLK - 1) / NBLK;
  float*    dis   = (float*)   alloc((size_t)N * 4);
  float*    dinv  = (float*)   alloc((size_t)N * 4);
  int*      rowp  = (int*)     alloc((size_t)(N + 1) * 4);
  int*      bhist = (int*)     alloc((size_t)NBLK * B * 4);
  int*      bs    = (int*)     alloc((size_t)(B + 1) * 4);
  int2*     tmp   = (int2*)    alloc((size_t)E * 8);
  int*      ep    = (int*)     alloc((size_t)E * 4);
  float*    wt    = (float*)   alloc((size_t)E * 4);
  _Float16* Xh    = (_Float16*)alloc((size_t)N * 128 * 2);
  _Float16* W1t   = (_Float16*)alloc((size_t)128 * 128 * 2);
  _Float16* W2t   = (_Float16*)alloc((size_t)64 * 128 * 2);
  __half*   bufA  = (__half*)  alloc((size_t)N * 128 * 2);
  __half*   bufB  = (__half*)  alloc((size_t)N * 128 * 2);
  __half*   bufC  = (__half*)  alloc((size_t)N * 64 * 2);
  __half*   z     = (__half*)  alloc((size_t)N * 64 * 2);
  (void)ws_size; (void)n_in; (void)out_size;

  const int* row = eidx;      // edge_index[0]
  const int* col = eidx + E;  // edge_index[1]
  const int n4 = N * 32;      // N*128/4 float4 groups
  const int TG = (N + 63) / 64;  // gemm tiles (782) >= B (196)

  // k1: prep + hist fused
  prep_hist_kernel<<<2048, 256, 0, stream>>>(x, W1, W2, Xh, W1t, W2t, n4,
                                             col, bhist, E, chunk, B);
  // k2: scatter with fused base computation
  scatter_base_kernel<<<NBLK, 256, 0, stream>>>(row, col, bhist, tmp, bs, E, chunk, B);
  // k3: CSR finalize + gemm1 fused (bufA = half(Xh@W1))
  csr_gemm1_kernel<<<TG, 256, 0, stream>>>(tmp, bs, rowp, dis, dinv, ep, N, B,
                                           Xh, W1t, (_Float16*)bufA);
  // k4: bufB = half(relu(agg(bufA)+dinv*bufA+b1)); caches wt[]
  agg128h_kernel<true><<<(N + 3) / 4, 256, 0, stream>>>(bufA, rowp, ep, dis, wt,
                                                        dinv, b1, bufB, N);
  // k5: bufC = half(bufB@W2)
  gemm_mfma_kernel<64><<<TG, 256, 0, stream>>>((const _Float16*)bufB, W2t,
                                               (_Float16*)bufC, N);
  // k6: z = half(agg(bufC)+dinv*bufC+b2) using cached wt[]
  agg64h_kernel<false><<<(N + 3) / 4, 256, 0, stream>>>(bufC, rowp, ep, wt, dis,
                                                        dinv, b2, z, N);
  // k7: decode
  decode_kernel<<<(NL + 3) / 4, 256, 0, stream>>>(z, eli, out, NL);
}

// Round 4
// 244.554 us; speedup vs baseline: 3.5334x; 1.0100x over previous
//
#include <hip/hip_runtime.h>
#include <hip/hip_bf16.h>
#include <hip/hip_fp16.h>

// ---------------------------------------------------------------------------
// GCN link prediction (math fp32, fp16 tables, MFMA GEMMs).
// Round 18: 7 dispatches; MLP (memory-level parallelism) boost in the three
// latency-bound gather kernels (agg128 was #1 at 42.7us, HBM 30% / VALU 41% /
// no pipe saturated):
//  - agg128: 4 edge-groups in flight (16 edges/iter, was 8)
//  - agg64:  4 oct-groups in flight (32 edges/iter, was 16)
//  - decode: 4 pairs per wave, batched gathers (was 1 pair/wave)
//   k1 prep+hist   (2048 blocks)
//   k2 scatter+base(256 blocks)
//   k3 csr+gemm1   (782 blocks)
//   k4 agg128+relu (12500 blocks)
//   k5 gemm2       (782 blocks)
//   k6 agg64       (12500 blocks)
//   k7 decode      (12500 blocks)
// ---------------------------------------------------------------------------

typedef _Float16 half8 __attribute__((ext_vector_type(8)));
typedef _Float16 half4v __attribute__((ext_vector_type(4)));
typedef float   floatx4 __attribute__((ext_vector_type(4)));

#define NBLK 256  // blocks for edge-chunk passes (hist/scatter chunking)

// ---------------------------------------------------------------------------

template<int M>
__device__ __forceinline__ void gemm_tile(const _Float16* __restrict__ Xh,
                                          const _Float16* __restrict__ Wt,
                                          _Float16* __restrict__ Y,
                                          int N, int tile, int t) {
  constexpr int K = 128;
  constexpr int CT = M / 16;
  const int lane = t & 63;
  const int i16 = lane & 15;
  const int quad = lane >> 4;
  const int row0 = tile * 64 + (t >> 6) * 16;
  int arow = row0 + i16;
  if (arow >= N) arow = N - 1;
  const _Float16* aptr = Xh + (size_t)arow * K + quad * 8;
  floatx4 acc[CT];
#pragma unroll
  for (int c = 0; c < CT; ++c) acc[c] = (floatx4){0.f, 0.f, 0.f, 0.f};
#pragma unroll
  for (int k0 = 0; k0 < K; k0 += 32) {
    half8 a = *(const half8*)(aptr + k0);
#pragma unroll
    for (int c = 0; c < CT; ++c) {
      half8 b = *(const half8*)(Wt + (size_t)(c * 16 + i16) * K + quad * 8 + k0);
      acc[c] = __builtin_amdgcn_mfma_f32_16x16x32_f16(a, b, acc[c], 0, 0, 0);
    }
  }
#pragma unroll
  for (int c = 0; c < CT; ++c) {
#pragma unroll
    for (int r = 0; r < 4; ++r) {
      int gr = row0 + quad * 4 + r;
      if (gr < N) Y[(size_t)gr * M + c * 16 + i16] = (_Float16)acc[c][r];
    }
  }
}

// ---------------------------------------------------------------------------
// k1: fused prep + per-chunk bucket histogram.
// ---------------------------------------------------------------------------
__global__ __launch_bounds__(256)
void prep_hist_kernel(const float* __restrict__ x, const float* __restrict__ W1,
                      const float* __restrict__ W2, _Float16* __restrict__ Xh,
                      _Float16* __restrict__ W1t, _Float16* __restrict__ W2t,
                      int n4, const int* __restrict__ col,
                      int* __restrict__ bhist, int ne, int chunk, int B) {
  int t = threadIdx.x, blk = blockIdx.x;
  if (blk < NBLK) {   // histogram part
    __shared__ int h[256];
    for (int b = t; b < B; b += 256) h[b] = 0;
    __syncthreads();
    int e0 = blk * chunk, e1 = min(ne, e0 + chunk);
    for (int i = e0 + t; i < e1; i += 256)
      atomicAdd(&h[col[i] >> 8], 1);
    __syncthreads();
    for (int b = t; b < B; b += 256) bhist[blk * B + b] = h[b];
  }
  // prep part: all blocks grid-stride
  const int gs = gridDim.x * 256;
  for (int i = blk * 256 + t; i < n4; i += gs) {
    float4 v = ((const float4*)x)[i];
    half4v h4; h4[0] = (_Float16)v.x; h4[1] = (_Float16)v.y;
    h4[2] = (_Float16)v.z; h4[3] = (_Float16)v.w;
    ((half4v*)Xh)[i] = h4;
    if (i < 128 * 128) { int k = i >> 7, n = i & 127; W1t[(size_t)n * 128 + k] = (_Float16)W1[i]; }
    if (i < 128 * 64)  { int k = i >> 6, n = i & 63;  W2t[(size_t)n * 128 + k] = (_Float16)W2[i]; }
  }
}

// ---------------------------------------------------------------------------
// k2: scatter with base computation fused.
// ---------------------------------------------------------------------------
__global__ __launch_bounds__(256)
void scatter_base_kernel(const int* __restrict__ row, const int* __restrict__ col,
                         const int* __restrict__ bhist, int2* __restrict__ tmp,
                         int* __restrict__ bs, int ne, int chunk, int B) {
  __shared__ int tot[256], my[256], start[257];
  int t = threadIdx.x, blk = blockIdx.x;
  if (t < B) {
    int s = 0, sp = 0;
    for (int b2 = 0; b2 < NBLK; ++b2) {
      int v = bhist[b2 * B + t];
      s += v;
      if (b2 < blk) sp += v;
    }
    tot[t] = s; my[t] = sp;
  }
  __syncthreads();
  if (t == 0) {
    int run = 0;
    for (int b = 0; b < B; ++b) { start[b] = run; run += tot[b]; }
    start[B] = run;
  }
  __syncthreads();
  if (blk == 0 && t <= B) bs[t] = start[t];
  if (t < B) tot[t] = start[t] + my[t];   // reuse tot[] as this block's cursors
  __syncthreads();
  int e0 = blk * chunk, e1 = min(ne, e0 + chunk);
  for (int i = e0 + t; i < e1; i += 256) {
    int c = col[i];
    int pos = atomicAdd(&tot[c >> 8], 1);
    tmp[pos] = make_int2(row[i], c);
  }
}

// ---------------------------------------------------------------------------
// k3: fused per-bucket CSR finalize + gemm1.
// ---------------------------------------------------------------------------
__global__ __launch_bounds__(256)
void csr_gemm1_kernel(const int2* __restrict__ tmp, const int* __restrict__ bs,
                      int* __restrict__ rowp, float* __restrict__ dis,
                      float* __restrict__ dinv, int* __restrict__ ep, int n, int B,
                      const _Float16* __restrict__ Xh, const _Float16* __restrict__ W1t,
                      _Float16* __restrict__ Y) {
  int t = threadIdx.x, b = blockIdx.x;
  if (b < B) {
    __shared__ int h[256], lo[256], cur[256];
    h[t] = 0;
    __syncthreads();
    int s0 = bs[b], s1 = bs[b + 1];
    for (int i = s0 + t; i < s1; i += 256)
      atomicAdd(&h[tmp[i].y & 255], 1);
    __syncthreads();
    if (t == 0) {
      int run = 0;
      for (int cb = 0; cb < 256; ++cb) { lo[cb] = run; run += h[cb]; }
    }
    __syncthreads();
    cur[t] = lo[t];
    int node = (b << 8) + t;
    if (node < n) {
      int c = h[t];
      rowp[node] = s0 + lo[t];
      float d = (float)(c + 1);   // +1 self loop
      dinv[node] = 1.0f / d;
      dis[node]  = rsqrtf(d);
      if (node == n - 1) rowp[n] = s1;   // last bucket end == E
    }
    __syncthreads();
    for (int i = s0 + t; i < s1; i += 256) {
      int2 rc = tmp[i];
      int r = atomicAdd(&cur[rc.y & 255], 1);
      ep[s0 + r] = rc.x;
    }
  }
  gemm_tile<128>(Xh, W1t, Y, n, b, t);
}

// ---------------------------------------------------------------------------
// k4: CH=128 aggregation, direct-load quarter scheme, 4 groups in flight
// (16 edges/iter). Caches wt[e] = dis[src] for the second pass.
// ---------------------------------------------------------------------------
template<bool RELU>
__global__ __launch_bounds__(256)
void agg128h_kernel(const __half* __restrict__ xw, const int* __restrict__ row_ptr,
                    const int* __restrict__ ep, const float* __restrict__ dis,
                    float* __restrict__ wt, const float* __restrict__ deg_inv,
                    const float* __restrict__ bias, __half* __restrict__ out, int n) {
  int wave = (blockIdx.x * 256 + threadIdx.x) >> 6;
  int lane = threadIdx.x & 63;
  if (wave >= n) return;
  const int node = wave;
  const int s0 = row_ptr[node], s1 = row_ptr[node + 1];
  const int sub = lane & 15;
  const int q = lane >> 4;
  const float disc = dis[node];
  float acc[4][8];
#pragma unroll
  for (int g = 0; g < 4; ++g)
#pragma unroll
    for (int j = 0; j < 8; ++j) acc[g][j] = 0.f;
  for (int e = s0; e < s1; e += 16) {
#pragma unroll
    for (int g = 0; g < 4; ++g) {
      int eg = e + 4 * g + q;
      if (e + 4 * g >= s1) break;            // wave-uniform per group
      int cg = min(eg, s1 - 1);
      int sg = ep[cg];
      float dg = dis[sg];
      float4 raw = ((const float4*)(xw + (size_t)sg * 128))[sub];
      if (sub == 0 && eg < s1) wt[eg] = dg;
      float wg = (eg < s1) ? dg * disc : 0.f;
      const __half2* hp = (const __half2*)&raw;
#pragma unroll
      for (int j = 0; j < 4; ++j) {
        float2 v = __half22float2(hp[j]);
        acc[g][2 * j]     = fmaf(wg, v.x, acc[g][2 * j]);
        acc[g][2 * j + 1] = fmaf(wg, v.y, acc[g][2 * j + 1]);
      }
    }
  }
#pragma unroll
  for (int j = 0; j < 8; ++j) {
    float s = (acc[0][j] + acc[1][j]) + (acc[2][j] + acc[3][j]);
    s += __shfl_xor(s, 16, 64);
    s += __shfl_xor(s, 32, 64);
    acc[0][j] = s;
  }
  if (q == 0) {
    float di = deg_inv[node];
    float4 sraw = ((const float4*)(xw + (size_t)node * 128))[sub];
    const __half2* sp = (const __half2*)&sraw;
    const float4* bp = (const float4*)(bias + 8 * sub);
    float o[8];
#pragma unroll
    for (int j = 0; j < 4; ++j) {
      float2 sv = __half22float2(sp[j]);
      o[2 * j]     = acc[0][2 * j]     + sv.x * di;
      o[2 * j + 1] = acc[0][2 * j + 1] + sv.y * di;
    }
    float4 b0 = bp[0], b1v = bp[1];
    o[0] += b0.x; o[1] += b0.y; o[2] += b0.z; o[3] += b0.w;
    o[4] += b1v.x; o[5] += b1v.y; o[6] += b1v.z; o[7] += b1v.w;
    if (RELU) {
#pragma unroll
      for (int j = 0; j < 8; ++j) o[j] = fmaxf(o[j], 0.f);
    }
    __half2 h2[4];
#pragma unroll
    for (int j = 0; j < 4; ++j)
      h2[j] = __float22half2_rn(make_float2(o[2 * j], o[2 * j + 1]));
    *(float4*)(out + (size_t)node * 128 + 8 * sub) = *(const float4*)h2;
  }
}

// ---------------------------------------------------------------------------
// k6: CH=64 aggregation, direct-load OCT scheme, 4 groups in flight
// (32 edges/iter). Weights from wt[] (cached by agg128).
// ---------------------------------------------------------------------------
template<bool RELU>
__global__ __launch_bounds__(256)
void agg64h_kernel(const __half* __restrict__ xw, const int* __restrict__ row_ptr,
                   const int* __restrict__ ep, const float* __restrict__ wt,
                   const float* __restrict__ dis, const float* __restrict__ deg_inv,
                   const float* __restrict__ bias, __half* __restrict__ out, int n) {
  int wave = (blockIdx.x * 256 + threadIdx.x) >> 6;
  int lane = threadIdx.x & 63;
  if (wave >= n) return;
  const int node = wave;
  const int s0 = row_ptr[node], s1 = row_ptr[node + 1];
  const int sub = lane & 7;       // 8 lanes x 16B = 128B row (8 ch each)
  const int oct = lane >> 3;      // 8 edges per group
  const float disc = dis[node];
  float acc[4][8];
#pragma unroll
  for (int g = 0; g < 4; ++g)
#pragma unroll
    for (int j = 0; j < 8; ++j) acc[g][j] = 0.f;
  for (int e = s0; e < s1; e += 32) {
#pragma unroll
    for (int g = 0; g < 4; ++g) {
      int eg = e + 8 * g + oct;
      if (e + 8 * g >= s1) break;            // wave-uniform per group
      int cg = min(eg, s1 - 1);
      int sg = ep[cg];
      float wg = (eg < s1) ? wt[cg] * disc : 0.f;
      float4 raw = ((const float4*)(xw + (size_t)sg * 64))[sub];
      const __half2* hp = (const __half2*)&raw;
#pragma unroll
      for (int j = 0; j < 4; ++j) {
        float2 v = __half22float2(hp[j]);
        acc[g][2 * j]     = fmaf(wg, v.x, acc[g][2 * j]);
        acc[g][2 * j + 1] = fmaf(wg, v.y, acc[g][2 * j + 1]);
      }
    }
  }
#pragma unroll
  for (int j = 0; j < 8; ++j) {
    float s = (acc[0][j] + acc[1][j]) + (acc[2][j] + acc[3][j]);
    s += __shfl_xor(s, 8, 64);
    s += __shfl_xor(s, 16, 64);
    s += __shfl_xor(s, 32, 64);
    acc[0][j] = s;
  }
  if (oct == 0) {
    float di = deg_inv[node];
    float4 sraw = ((const float4*)(xw + (size_t)node * 64))[sub];
    const __half2* sp = (const __half2*)&sraw;
    const float4* bp = (const float4*)(bias + 8 * sub);
    float o[8];
#pragma unroll
    for (int j = 0; j < 4; ++j) {
      float2 sv = __half22float2(sp[j]);
      o[2 * j]     = acc[0][2 * j]     + sv.x * di;
      o[2 * j + 1] = acc[0][2 * j + 1] + sv.y * di;
    }
    float4 b0 = bp[0], b1v = bp[1];
    o[0] += b0.x; o[1] += b0.y; o[2] += b0.z; o[3] += b0.w;
    o[4] += b1v.x; o[5] += b1v.y; o[6] += b1v.z; o[7] += b1v.w;
    if (RELU) {
#pragma unroll
      for (int j = 0; j < 8; ++j) o[j] = fmaxf(o[j], 0.f);
    }
    __half2 h2[4];
#pragma unroll
    for (int j = 0; j < 4; ++j)
      h2[j] = __float22half2_rn(make_float2(o[2 * j], o[2 * j + 1]));
    *(float4*)(out + (size_t)node * 64 + 8 * sub) = *(const float4*)h2;
  }
}

// k5: standalone gemm2.
template<int M>
__global__ __launch_bounds__(256)
void gemm_mfma_kernel(const _Float16* __restrict__ Xh,
                      const _Float16* __restrict__ Wt,
                      _Float16* __restrict__ Y, int N) {
  gemm_tile<M>(Xh, Wt, Y, N, blockIdx.x, threadIdx.x);
}

// ---------------------------------------------------------------------------
// k7: decode — 4 pairs per wave, gathers batched before reductions (ILP 4).
// ---------------------------------------------------------------------------
__global__ __launch_bounds__(256)
void decode_kernel(const __half* __restrict__ z, const int* __restrict__ eli,
                   float* __restrict__ out, int nl) {
  int wave = (blockIdx.x * 256 + threadIdx.x) >> 6;
  int lane = threadIdx.x & 63;
  int p0 = wave * 4;
  if (p0 >= nl) return;
  int sub = lane & 31;
  float2 v[4];
#pragma unroll
  for (int j = 0; j < 4; ++j) {
    int p = p0 + j;
    int src = 0, dst = 0;
    if (p < nl) { src = eli[p]; dst = eli[nl + p]; }
    int node = (lane < 32) ? src : dst;
    v[j] = __half22float2(((const __half2*)(z + (size_t)node * 64))[sub]);
  }
#pragma unroll
  for (int j = 0; j < 4; ++j) {
    int p = p0 + j;
    float ox = __shfl_xor(v[j].x, 32, 64);
    float oy = __shfl_xor(v[j].y, 32, 64);
    float pr = v[j].x * ox + v[j].y * oy;
#pragma unroll
    for (int m = 16; m >= 1; m >>= 1) pr += __shfl_xor(pr, m, 64);
    if (lane == 0 && p < nl) out[p] = pr;
  }
}

// ---------------------------------------------------------------------------

extern "C" void kernel_launch(void* const* d_in, const int* in_sizes, int n_in,
                              void* d_out, int out_size, void* d_ws, size_t ws_size,
                              hipStream_t stream) {
  const float* x  = (const float*)d_in[0];
  const float* W1 = (const float*)d_in[1];
  const float* b1 = (const float*)d_in[2];
  const float* W2 = (const float*)d_in[3];
  const float* b2 = (const float*)d_in[4];
  const int* eidx = (const int*)d_in[5];
  const int* eli  = (const int*)d_in[6];
  const int N  = in_sizes[0] / 128;
  const int E  = in_sizes[5] / 2;
  const int NL = in_sizes[6] / 2;
  float* out = (float*)d_out;

  char* ws = (char*)d_ws;
  size_t off = 0;
  auto alloc = [&](size_t bytes) -> char* {
    char* p = ws + off;
    off = (off + bytes + 255) & ~(size_t)255;
    return p;
  };
  const int B = (N + 255) / 256;        // buckets (col>>8); needs N <= 65536
  const int chunk = (E + NBLK - 1) / NBLK;
  float*    dis   = (float*)   alloc((size_t)N * 4);
  float*    dinv  = (float*)   alloc((size_t)N * 4);
  int*      rowp  = (int*)     alloc((size_t)(N + 1) * 4);
  int*      bhist = (int*)     alloc((size_t)NBLK * B * 4);
  int*      bs    = (int*)     alloc((size_t)(B + 1) * 4);
  int2*     tmp   = (int2*)    alloc((size_t)E * 8);
  int*      ep    = (int*)     alloc((size_t)E * 4);
  float*    wt    = (float*)   alloc((size_t)E * 4);
  _Float16* Xh    = (_Float16*)alloc((size_t)N * 128 * 2);
  _Float16* W1t   = (_Float16*)alloc((size_t)128 * 128 * 2);
  _Float16* W2t   = (_Float16*)alloc((size_t)64 * 128 * 2);
  __half*   bufA  = (__half*)  alloc((size_t)N * 128 * 2);
  __half*   bufB  = (__half*)  alloc((size_t)N * 128 * 2);
  __half*   bufC  = (__half*)  alloc((size_t)N * 64 * 2);
  __half*   z     = (__half*)  alloc((size_t)N * 64 * 2);
  (void)ws_size; (void)n_in; (void)out_size;

  const int* row = eidx;      // edge_index[0]
  const int* col = eidx + E;  // edge_index[1]
  const int n4 = N * 32;      // N*128/4 float4 groups
  const int TG = (N + 63) / 64;  // gemm tiles (782) >= B (196)

  // k1: prep + hist fused
  prep_hist_kernel<<<2048, 256, 0, stream>>>(x, W1, W2, Xh, W1t, W2t, n4,
                                             col, bhist, E, chunk, B);
  // k2: scatter with fused base computation
  scatter_base_kernel<<<NBLK, 256, 0, stream>>>(row, col, bhist, tmp, bs, E, chunk, B);
  // k3: CSR finalize + gemm1 fused (bufA = half(Xh@W1))
  csr_gemm1_kernel<<<TG, 256, 0, stream>>>(tmp, bs, rowp, dis, dinv, ep, N, B,
                                           Xh, W1t, (_Float16*)bufA);
  // k4: bufB = half(relu(agg(bufA)+dinv*bufA+b1)); caches wt[]
  agg128h_kernel<true><<<(N + 3) / 4, 256, 0, stream>>>(bufA, rowp, ep, dis, wt,
                                                        dinv, b1, bufB, N);
  // k5: bufC = half(bufB@W2)
  gemm_mfma_kernel<64><<<TG, 256, 0, stream>>>((const _Float16*)bufB, W2t,
                                               (_Float16*)bufC, N);
  // k6: z = half(agg(bufC)+dinv*bufC+b2) using cached wt[]
  agg64h_kernel<false><<<(N + 3) / 4, 256, 0, stream>>>(bufC, rowp, ep, wt, dis,
                                                        dinv, b2, z, N);
  // k7: decode (4 pairs/wave)
  decode_kernel<<<(NL + 15) / 16, 256, 0, stream>>>(z, eli, out, NL);
}

// Round 5
// 226.176 us; speedup vs baseline: 3.8205x; 1.0813x over previous
//
#include <hip/hip_runtime.h>
#include <hip/hip_bf16.h>
#include <hip/hip_fp16.h>

// ---------------------------------------------------------------------------
// GCN link prediction (math fp32, fp16 tables, MFMA GEMMs).
// Round 19: 7 dispatches. Fix round-18's agg regression: the per-group
// `break` inside the unrolled loop serialized the gather chains (MLP->1,
// agg128 42.7->49.6us). Now branch-free straight-line bodies: all 4 groups'
// loads issue unconditionally (clamped index, zero weight for OOB), FMAs
// after. acc[g&1] keeps VGPR below the 64-reg occupancy cliff.
//   k1 prep+hist   (2048 blocks)
//   k2 scatter+base(256 blocks)
//   k3 csr+gemm1   (782 blocks)
//   k4 agg128+relu (12500 blocks)
//   k5 gemm2       (782 blocks)
//   k6 agg64       (12500 blocks)
//   k7 decode      (12500 blocks)
// ---------------------------------------------------------------------------

typedef _Float16 half8 __attribute__((ext_vector_type(8)));
typedef _Float16 half4v __attribute__((ext_vector_type(4)));
typedef float   floatx4 __attribute__((ext_vector_type(4)));

#define NBLK 256  // blocks for edge-chunk passes (hist/scatter chunking)

// ---------------------------------------------------------------------------

template<int M>
__device__ __forceinline__ void gemm_tile(const _Float16* __restrict__ Xh,
                                          const _Float16* __restrict__ Wt,
                                          _Float16* __restrict__ Y,
                                          int N, int tile, int t) {
  constexpr int K = 128;
  constexpr int CT = M / 16;
  const int lane = t & 63;
  const int i16 = lane & 15;
  const int quad = lane >> 4;
  const int row0 = tile * 64 + (t >> 6) * 16;
  int arow = row0 + i16;
  if (arow >= N) arow = N - 1;
  const _Float16* aptr = Xh + (size_t)arow * K + quad * 8;
  floatx4 acc[CT];
#pragma unroll
  for (int c = 0; c < CT; ++c) acc[c] = (floatx4){0.f, 0.f, 0.f, 0.f};
#pragma unroll
  for (int k0 = 0; k0 < K; k0 += 32) {
    half8 a = *(const half8*)(aptr + k0);
#pragma unroll
    for (int c = 0; c < CT; ++c) {
      half8 b = *(const half8*)(Wt + (size_t)(c * 16 + i16) * K + quad * 8 + k0);
      acc[c] = __builtin_amdgcn_mfma_f32_16x16x32_f16(a, b, acc[c], 0, 0, 0);
    }
  }
#pragma unroll
  for (int c = 0; c < CT; ++c) {
#pragma unroll
    for (int r = 0; r < 4; ++r) {
      int gr = row0 + quad * 4 + r;
      if (gr < N) Y[(size_t)gr * M + c * 16 + i16] = (_Float16)acc[c][r];
    }
  }
}

// ---------------------------------------------------------------------------
// k1: fused prep + per-chunk bucket histogram.
// ---------------------------------------------------------------------------
__global__ __launch_bounds__(256)
void prep_hist_kernel(const float* __restrict__ x, const float* __restrict__ W1,
                      const float* __restrict__ W2, _Float16* __restrict__ Xh,
                      _Float16* __restrict__ W1t, _Float16* __restrict__ W2t,
                      int n4, const int* __restrict__ col,
                      int* __restrict__ bhist, int ne, int chunk, int B) {
  int t = threadIdx.x, blk = blockIdx.x;
  if (blk < NBLK) {   // histogram part
    __shared__ int h[256];
    for (int b = t; b < B; b += 256) h[b] = 0;
    __syncthreads();
    int e0 = blk * chunk, e1 = min(ne, e0 + chunk);
    for (int i = e0 + t; i < e1; i += 256)
      atomicAdd(&h[col[i] >> 8], 1);
    __syncthreads();
    for (int b = t; b < B; b += 256) bhist[blk * B + b] = h[b];
  }
  // prep part: all blocks grid-stride
  const int gs = gridDim.x * 256;
  for (int i = blk * 256 + t; i < n4; i += gs) {
    float4 v = ((const float4*)x)[i];
    half4v h4; h4[0] = (_Float16)v.x; h4[1] = (_Float16)v.y;
    h4[2] = (_Float16)v.z; h4[3] = (_Float16)v.w;
    ((half4v*)Xh)[i] = h4;
    if (i < 128 * 128) { int k = i >> 7, n = i & 127; W1t[(size_t)n * 128 + k] = (_Float16)W1[i]; }
    if (i < 128 * 64)  { int k = i >> 6, n = i & 63;  W2t[(size_t)n * 128 + k] = (_Float16)W2[i]; }
  }
}

// ---------------------------------------------------------------------------
// k2: scatter with base computation fused.
// ---------------------------------------------------------------------------
__global__ __launch_bounds__(256)
void scatter_base_kernel(const int* __restrict__ row, const int* __restrict__ col,
                         const int* __restrict__ bhist, int2* __restrict__ tmp,
                         int* __restrict__ bs, int ne, int chunk, int B) {
  __shared__ int tot[256], my[256], start[257];
  int t = threadIdx.x, blk = blockIdx.x;
  if (t < B) {
    int s = 0, sp = 0;
    for (int b2 = 0; b2 < NBLK; ++b2) {
      int v = bhist[b2 * B + t];
      s += v;
      if (b2 < blk) sp += v;
    }
    tot[t] = s; my[t] = sp;
  }
  __syncthreads();
  if (t == 0) {
    int run = 0;
    for (int b = 0; b < B; ++b) { start[b] = run; run += tot[b]; }
    start[B] = run;
  }
  __syncthreads();
  if (blk == 0 && t <= B) bs[t] = start[t];
  if (t < B) tot[t] = start[t] + my[t];   // reuse tot[] as this block's cursors
  __syncthreads();
  int e0 = blk * chunk, e1 = min(ne, e0 + chunk);
  for (int i = e0 + t; i < e1; i += 256) {
    int c = col[i];
    int pos = atomicAdd(&tot[c >> 8], 1);
    tmp[pos] = make_int2(row[i], c);
  }
}

// ---------------------------------------------------------------------------
// k3: fused per-bucket CSR finalize + gemm1.
// ---------------------------------------------------------------------------
__global__ __launch_bounds__(256)
void csr_gemm1_kernel(const int2* __restrict__ tmp, const int* __restrict__ bs,
                      int* __restrict__ rowp, float* __restrict__ dis,
                      float* __restrict__ dinv, int* __restrict__ ep, int n, int B,
                      const _Float16* __restrict__ Xh, const _Float16* __restrict__ W1t,
                      _Float16* __restrict__ Y) {
  int t = threadIdx.x, b = blockIdx.x;
  if (b < B) {
    __shared__ int h[256], lo[256], cur[256];
    h[t] = 0;
    __syncthreads();
    int s0 = bs[b], s1 = bs[b + 1];
    for (int i = s0 + t; i < s1; i += 256)
      atomicAdd(&h[tmp[i].y & 255], 1);
    __syncthreads();
    if (t == 0) {
      int run = 0;
      for (int cb = 0; cb < 256; ++cb) { lo[cb] = run; run += h[cb]; }
    }
    __syncthreads();
    cur[t] = lo[t];
    int node = (b << 8) + t;
    if (node < n) {
      int c = h[t];
      rowp[node] = s0 + lo[t];
      float d = (float)(c + 1);   // +1 self loop
      dinv[node] = 1.0f / d;
      dis[node]  = rsqrtf(d);
      if (node == n - 1) rowp[n] = s1;   // last bucket end == E
    }
    __syncthreads();
    for (int i = s0 + t; i < s1; i += 256) {
      int2 rc = tmp[i];
      int r = atomicAdd(&cur[rc.y & 255], 1);
      ep[s0 + r] = rc.x;
    }
  }
  gemm_tile<128>(Xh, W1t, Y, n, b, t);
}

// ---------------------------------------------------------------------------
// k4: CH=128 aggregation, quarter scheme, 4 groups (16 edges) in flight,
// branch-free body: all loads unconditional (clamped), weights masked.
// Caches wt[e] = dis[src] for the second pass.
// ---------------------------------------------------------------------------
template<bool RELU>
__global__ __launch_bounds__(256)
void agg128h_kernel(const __half* __restrict__ xw, const int* __restrict__ row_ptr,
                    const int* __restrict__ ep, const float* __restrict__ dis,
                    float* __restrict__ wt, const float* __restrict__ deg_inv,
                    const float* __restrict__ bias, __half* __restrict__ out, int n) {
  int wave = (blockIdx.x * 256 + threadIdx.x) >> 6;
  int lane = threadIdx.x & 63;
  if (wave >= n) return;
  const int node = wave;
  const int s0 = row_ptr[node], s1 = row_ptr[node + 1];
  const int sub = lane & 15;
  const int q = lane >> 4;
  const float disc = dis[node];
  float acc[2][8];
#pragma unroll
  for (int g = 0; g < 2; ++g)
#pragma unroll
    for (int j = 0; j < 8; ++j) acc[g][j] = 0.f;
  for (int e = s0; e < s1; e += 16) {
    int eg[4], sg[4];
#pragma unroll
    for (int g = 0; g < 4; ++g) {
      eg[g] = e + 4 * g + q;
      int cg = min(eg[g], s1 - 1);
      sg[g] = ep[cg];
    }
    float dg[4]; float4 raw[4];
#pragma unroll
    for (int g = 0; g < 4; ++g) {
      dg[g] = dis[sg[g]];
      raw[g] = ((const float4*)(xw + (size_t)sg[g] * 128))[sub];
    }
#pragma unroll
    for (int g = 0; g < 4; ++g) {
      bool ok = eg[g] < s1;
      if (sub == 0 && ok) wt[eg[g]] = dg[g];
      float wg = ok ? dg[g] * disc : 0.f;
      const __half2* hp = (const __half2*)&raw[g];
#pragma unroll
      for (int j = 0; j < 4; ++j) {
        float2 v = __half22float2(hp[j]);
        acc[g & 1][2 * j]     = fmaf(wg, v.x, acc[g & 1][2 * j]);
        acc[g & 1][2 * j + 1] = fmaf(wg, v.y, acc[g & 1][2 * j + 1]);
      }
    }
  }
#pragma unroll
  for (int j = 0; j < 8; ++j) {
    float s = acc[0][j] + acc[1][j];
    s += __shfl_xor(s, 16, 64);
    s += __shfl_xor(s, 32, 64);
    acc[0][j] = s;
  }
  if (q == 0) {
    float di = deg_inv[node];
    float4 sraw = ((const float4*)(xw + (size_t)node * 128))[sub];
    const __half2* sp = (const __half2*)&sraw;
    const float4* bp = (const float4*)(bias + 8 * sub);
    float o[8];
#pragma unroll
    for (int j = 0; j < 4; ++j) {
      float2 sv = __half22float2(sp[j]);
      o[2 * j]     = acc[0][2 * j]     + sv.x * di;
      o[2 * j + 1] = acc[0][2 * j + 1] + sv.y * di;
    }
    float4 b0 = bp[0], b1v = bp[1];
    o[0] += b0.x; o[1] += b0.y; o[2] += b0.z; o[3] += b0.w;
    o[4] += b1v.x; o[5] += b1v.y; o[6] += b1v.z; o[7] += b1v.w;
    if (RELU) {
#pragma unroll
      for (int j = 0; j < 8; ++j) o[j] = fmaxf(o[j], 0.f);
    }
    __half2 h2[4];
#pragma unroll
    for (int j = 0; j < 4; ++j)
      h2[j] = __float22half2_rn(make_float2(o[2 * j], o[2 * j + 1]));
    *(float4*)(out + (size_t)node * 128 + 8 * sub) = *(const float4*)h2;
  }
}

// ---------------------------------------------------------------------------
// k6: CH=64 aggregation, OCT scheme, 4 groups (32 edges) in flight,
// branch-free body. Weights from wt[] (cached by agg128).
// ---------------------------------------------------------------------------
template<bool RELU>
__global__ __launch_bounds__(256)
void agg64h_kernel(const __half* __restrict__ xw, const int* __restrict__ row_ptr,
                   const int* __restrict__ ep, const float* __restrict__ wt,
                   const float* __restrict__ dis, const float* __restrict__ deg_inv,
                   const float* __restrict__ bias, __half* __restrict__ out, int n) {
  int wave = (blockIdx.x * 256 + threadIdx.x) >> 6;
  int lane = threadIdx.x & 63;
  if (wave >= n) return;
  const int node = wave;
  const int s0 = row_ptr[node], s1 = row_ptr[node + 1];
  const int sub = lane & 7;       // 8 lanes x 16B = 128B row (8 ch each)
  const int oct = lane >> 3;      // 8 edges per group
  const float disc = dis[node];
  float acc[2][8];
#pragma unroll
  for (int g = 0; g < 2; ++g)
#pragma unroll
    for (int j = 0; j < 8; ++j) acc[g][j] = 0.f;
  for (int e = s0; e < s1; e += 32) {
    int eg[4], sg[4]; float wv[4];
#pragma unroll
    for (int g = 0; g < 4; ++g) {
      eg[g] = e + 8 * g + oct;
      int cg = min(eg[g], s1 - 1);
      sg[g] = ep[cg];
      wv[g] = wt[cg];
    }
    float4 raw[4];
#pragma unroll
    for (int g = 0; g < 4; ++g)
      raw[g] = ((const float4*)(xw + (size_t)sg[g] * 64))[sub];
#pragma unroll
    for (int g = 0; g < 4; ++g) {
      float wg = (eg[g] < s1) ? wv[g] * disc : 0.f;
      const __half2* hp = (const __half2*)&raw[g];
#pragma unroll
      for (int j = 0; j < 4; ++j) {
        float2 v = __half22float2(hp[j]);
        acc[g & 1][2 * j]     = fmaf(wg, v.x, acc[g & 1][2 * j]);
        acc[g & 1][2 * j + 1] = fmaf(wg, v.y, acc[g & 1][2 * j + 1]);
      }
    }
  }
#pragma unroll
  for (int j = 0; j < 8; ++j) {
    float s = acc[0][j] + acc[1][j];
    s += __shfl_xor(s, 8, 64);
    s += __shfl_xor(s, 16, 64);
    s += __shfl_xor(s, 32, 64);
    acc[0][j] = s;
  }
  if (oct == 0) {
    float di = deg_inv[node];
    float4 sraw = ((const float4*)(xw + (size_t)node * 64))[sub];
    const __half2* sp = (const __half2*)&sraw;
    const float4* bp = (const float4*)(bias + 8 * sub);
    float o[8];
#pragma unroll
    for (int j = 0; j < 4; ++j) {
      float2 sv = __half22float2(sp[j]);
      o[2 * j]     = acc[0][2 * j]     + sv.x * di;
      o[2 * j + 1] = acc[0][2 * j + 1] + sv.y * di;
    }
    float4 b0 = bp[0], b1v = bp[1];
    o[0] += b0.x; o[1] += b0.y; o[2] += b0.z; o[3] += b0.w;
    o[4] += b1v.x; o[5] += b1v.y; o[6] += b1v.z; o[7] += b1v.w;
    if (RELU) {
#pragma unroll
      for (int j = 0; j < 8; ++j) o[j] = fmaxf(o[j], 0.f);
    }
    __half2 h2[4];
#pragma unroll
    for (int j = 0; j < 4; ++j)
      h2[j] = __float22half2_rn(make_float2(o[2 * j], o[2 * j + 1]));
    *(float4*)(out + (size_t)node * 64 + 8 * sub) = *(const float4*)h2;
  }
}

// k5: standalone gemm2.
template<int M>
__global__ __launch_bounds__(256)
void gemm_mfma_kernel(const _Float16* __restrict__ Xh,
                      const _Float16* __restrict__ Wt,
                      _Float16* __restrict__ Y, int N) {
  gemm_tile<M>(Xh, Wt, Y, N, blockIdx.x, threadIdx.x);
}

// ---------------------------------------------------------------------------
// k7: decode — 4 pairs per wave, gathers batched before reductions (ILP 4).
// ---------------------------------------------------------------------------
__global__ __launch_bounds__(256)
void decode_kernel(const __half* __restrict__ z, const int* __restrict__ eli,
                   float* __restrict__ out, int nl) {
  int wave = (blockIdx.x * 256 + threadIdx.x) >> 6;
  int lane = threadIdx.x & 63;
  int p0 = wave * 4;
  if (p0 >= nl) return;
  int sub = lane & 31;
  float2 v[4];
#pragma unroll
  for (int j = 0; j < 4; ++j) {
    int p = p0 + j;
    int src = 0, dst = 0;
    if (p < nl) { src = eli[p]; dst = eli[nl + p]; }
    int node = (lane < 32) ? src : dst;
    v[j] = __half22float2(((const __half2*)(z + (size_t)node * 64))[sub]);
  }
#pragma unroll
  for (int j = 0; j < 4; ++j) {
    int p = p0 + j;
    float ox = __shfl_xor(v[j].x, 32, 64);
    float oy = __shfl_xor(v[j].y, 32, 64);
    float pr = v[j].x * ox + v[j].y * oy;
#pragma unroll
    for (int m = 16; m >= 1; m >>= 1) pr += __shfl_xor(pr, m, 64);
    if (lane == 0 && p < nl) out[p] = pr;
  }
}

// ---------------------------------------------------------------------------

extern "C" void kernel_launch(void* const* d_in, const int* in_sizes, int n_in,
                              void* d_out, int out_size, void* d_ws, size_t ws_size,
                              hipStream_t stream) {
  const float* x  = (const float*)d_in[0];
  const float* W1 = (const float*)d_in[1];
  const float* b1 = (const float*)d_in[2];
  const float* W2 = (const float*)d_in[3];
  const float* b2 = (const float*)d_in[4];
  const int* eidx = (const int*)d_in[5];
  const int* eli  = (const int*)d_in[6];
  const int N  = in_sizes[0] / 128;
  const int E  = in_sizes[5] / 2;
  const int NL = in_sizes[6] / 2;
  float* out = (float*)d_out;

  char* ws = (char*)d_ws;
  size_t off = 0;
  auto alloc = [&](size_t bytes) -> char* {
    char* p = ws + off;
    off = (off + bytes + 255) & ~(size_t)255;
    return p;
  };
  const int B = (N + 255) / 256;        // buckets (col>>8); needs N <= 65536
  const int chunk = (E + NBLK - 1) / NBLK;
  float*    dis   = (float*)   alloc((size_t)N * 4);
  float*    dinv  = (float*)   alloc((size_t)N * 4);
  int*      rowp  = (int*)     alloc((size_t)(N + 1) * 4);
  int*      bhist = (int*)     alloc((size_t)NBLK * B * 4);
  int*      bs    = (int*)     alloc((size_t)(B + 1) * 4);
  int2*     tmp   = (int2*)    alloc((size_t)E * 8);
  int*      ep    = (int*)     alloc((size_t)E * 4);
  float*    wt    = (float*)   alloc((size_t)E * 4);
  _Float16* Xh    = (_Float16*)alloc((size_t)N * 128 * 2);
  _Float16* W1t   = (_Float16*)alloc((size_t)128 * 128 * 2);
  _Float16* W2t   = (_Float16*)alloc((size_t)64 * 128 * 2);
  __half*   bufA  = (__half*)  alloc((size_t)N * 128 * 2);
  __half*   bufB  = (__half*)  alloc((size_t)N * 128 * 2);
  __half*   bufC  = (__half*)  alloc((size_t)N * 64 * 2);
  __half*   z     = (__half*)  alloc((size_t)N * 64 * 2);
  (void)ws_size; (void)n_in; (void)out_size;

  const int* row = eidx;      // edge_index[0]
  const int* col = eidx + E;  // edge_index[1]
  const int n4 = N * 32;      // N*128/4 float4 groups
  const int TG = (N + 63) / 64;  // gemm tiles (782) >= B (196)

  // k1: prep + hist fused
  prep_hist_kernel<<<2048, 256, 0, stream>>>(x, W1, W2, Xh, W1t, W2t, n4,
                                             col, bhist, E, chunk, B);
  // k2: scatter with fused base computation
  scatter_base_kernel<<<NBLK, 256, 0, stream>>>(row, col, bhist, tmp, bs, E, chunk, B);
  // k3: CSR finalize + gemm1 fused (bufA = half(Xh@W1))
  csr_gemm1_kernel<<<TG, 256, 0, stream>>>(tmp, bs, rowp, dis, dinv, ep, N, B,
                                           Xh, W1t, (_Float16*)bufA);
  // k4: bufB = half(relu(agg(bufA)+dinv*bufA+b1)); caches wt[]
  agg128h_kernel<true><<<(N + 3) / 4, 256, 0, stream>>>(bufA, rowp, ep, dis, wt,
                                                        dinv, b1, bufB, N);
  // k5: bufC = half(bufB@W2)
  gemm_mfma_kernel<64><<<TG, 256, 0, stream>>>((const _Float16*)bufB, W2t,
                                               (_Float16*)bufC, N);
  // k6: z = half(agg(bufC)+dinv*bufC+b2) using cached wt[]
  agg64h_kernel<false><<<(N + 3) / 4, 256, 0, stream>>>(bufC, rowp, ep, wt, dis,
                                                        dinv, b2, z, N);
  // k7: decode (4 pairs/wave)
  decode_kernel<<<(NL + 15) / 16, 256, 0, stream>>>(z, eli, out, NL);
}